// Round 16
// baseline (4639.384 us; speedup 1.0000x reference)
//
#include <hip/hip_runtime.h>
#include <math.h>
#include <stdint.h>

#define N_IMG 64
#define S_LEN 257
#define D_MODEL 768
#define H_HEADS 12
#define L_LAYERS 12
#define F_HID 3072
#define OUT_DIM 10
#define R_ROWS (N_IMG * S_LEN)   // 16448
#define R_PAD 16512              // 129 * 128
#define SKV 320                  // padded key count for vT

typedef unsigned short ushort_t;
typedef __attribute__((ext_vector_type(4))) float f32x4;
typedef __attribute__((ext_vector_type(8))) short short8;
typedef __attribute__((ext_vector_type(2))) unsigned int u32x2;

__device__ __forceinline__ ushort_t f2bf(float x) {
    unsigned u = __float_as_uint(x);
    u += 0x7fffu + ((u >> 16) & 1u);
    return (ushort_t)(u >> 16);
}
__device__ __forceinline__ unsigned pack2(float a, float b) {
    return (unsigned)f2bf(a) | ((unsigned)f2bf(b) << 16);
}

// async global->LDS, 16B per lane; dest = wave-uniform base + lane*16
__device__ __forceinline__ void glds16(const ushort_t* g, const ushort_t* l) {
    __builtin_amdgcn_global_load_lds(
        (const __attribute__((address_space(1))) unsigned int*)(uintptr_t)g,
        (__attribute__((address_space(3))) unsigned int*)(uintptr_t)l,
        16, 0, 0);
}

// ---------------- positional embedding (double precision, matches numpy f64) ----------------
__global__ __launch_bounds__(256) void pos_kernel(float* __restrict__ pos) {
    int i = blockIdx.x;
    int t = threadIdx.x;
    for (int u = 0; u < 3; ++u) {
        int j = t + 256 * u;
        double e = (double)(j & ~1) / 768.0;
        double angle = (double)i * exp(-e * 9.210340371976184);
        double v = (j & 1) ? cos(angle) : sin(angle);
        pos[i * 768 + j] = (float)v;
    }
}

// ---------------- patch embed + cls + pos ----------------
__global__ __launch_bounds__(256) void embed_kernel(const float* __restrict__ images,
                                                    const float* __restrict__ Wemb,
                                                    const float* __restrict__ bemb,
                                                    const float* __restrict__ cls,
                                                    const float* __restrict__ pos,
                                                    float* __restrict__ tok) {
    int b = blockIdx.x;
    int n = b / S_LEN, s = b % S_LEN;
    int t = threadIdx.x;
    __shared__ float p[16];
    if (s > 0 && t < 16) p[t] = images[n * 4096 + (s - 1) * 16 + t];
    __syncthreads();
    for (int u = 0; u < 3; ++u) {
        int d = t + 256 * u;
        float acc;
        if (s == 0) {
            acc = cls[d];
        } else {
            acc = bemb[d];
            const float4* w = (const float4*)(Wemb + d * 16);
            float4 w0 = w[0], w1 = w[1], w2 = w[2], w3 = w[3];
            acc += p[0] * w0.x + p[1] * w0.y + p[2] * w0.z + p[3] * w0.w;
            acc += p[4] * w1.x + p[5] * w1.y + p[6] * w1.z + p[7] * w1.w;
            acc += p[8] * w2.x + p[9] * w2.y + p[10] * w2.z + p[11] * w2.w;
            acc += p[12] * w3.x + p[13] * w3.y + p[14] * w3.z + p[15] * w3.w;
        }
        tok[(size_t)b * 768 + d] = acc + pos[s * 768 + d];
    }
}

// ---------------- layernorm -> bf16 : one wave per row ----------------
__global__ __launch_bounds__(256) void ln_kernel(const float* __restrict__ x,
                                                 const float* __restrict__ g,
                                                 const float* __restrict__ b,
                                                 ushort_t* __restrict__ y) {
    int row = blockIdx.x * 4 + (threadIdx.x >> 6);
    int lane = threadIdx.x & 63;
    const float* xr = x + (size_t)row * 768 + lane * 4;
    float4 a0 = *(const float4*)xr;
    float4 a1 = *(const float4*)(xr + 256);
    float4 a2 = *(const float4*)(xr + 512);
    float s = (a0.x + a0.y + a0.z + a0.w) + (a1.x + a1.y + a1.z + a1.w) + (a2.x + a2.y + a2.z + a2.w);
    float sq = a0.x*a0.x + a0.y*a0.y + a0.z*a0.z + a0.w*a0.w
             + a1.x*a1.x + a1.y*a1.y + a1.z*a1.z + a1.w*a1.w
             + a2.x*a2.x + a2.y*a2.y + a2.z*a2.z + a2.w*a2.w;
    for (int o = 32; o; o >>= 1) {
        s += __shfl_xor(s, o);
        sq += __shfl_xor(sq, o);
    }
    float mu = s * (1.0f / 768.0f);
    float var = sq * (1.0f / 768.0f) - mu * mu;
    float rs = rsqrtf(var + 1e-5f);
    ushort_t* yr = y + (size_t)row * 768 + lane * 4;
#pragma unroll
    for (int i = 0; i < 3; ++i) {
        float4 av = (i == 0) ? a0 : (i == 1) ? a1 : a2;
        const float4 gg = *(const float4*)(g + lane * 4 + i * 256);
        const float4 bb = *(const float4*)(b + lane * 4 + i * 256);
        float o0 = (av.x - mu) * rs * gg.x + bb.x;
        float o1 = (av.y - mu) * rs * gg.y + bb.y;
        float o2 = (av.z - mu) * rs * gg.z + bb.z;
        float o3 = (av.w - mu) * rs * gg.w + bb.w;
        *(u32x2*)(yr + i * 256) = (u32x2){pack2(o0, o1), pack2(o2, o3)};
    }
}

// ---------------- per-layer weight conversion: wqkv pack + full W1 + full W2 ----------------
__global__ __launch_bounds__(256) void conv_layer(const float* __restrict__ Wq,
                                                  const float* __restrict__ Wk,
                                                  const float* __restrict__ Wv,
                                                  const float* __restrict__ W1l,
                                                  const float* __restrict__ W2l,
                                                  ushort_t* __restrict__ wqkvbf,
                                                  ushort_t* __restrict__ w1bf,
                                                  ushort_t* __restrict__ w2bf) {
    const int NQKV = H_HEADS * 192 * 64;       // 147456
    const int NW = F_HID * D_MODEL;            // 2359296
    int idx = (blockIdx.x * 256 + threadIdx.x) * 4;
    if (idx < NQKV) {
        int h = idx / (192 * 64);
        int rem = idx - h * 192 * 64;
        int o3 = rem >> 6, d = rem & 63;
        const float* src;
        int o;
        if (o3 < 64)       { src = Wq; o = o3; }
        else if (o3 < 128) { src = Wk; o = o3 - 64; }
        else               { src = Wv; o = o3 - 128; }
        float4 v = *(const float4*)(src + ((size_t)(h * 64 + o)) * 64 + d);
        *(u32x2*)(wqkvbf + idx) = (u32x2){pack2(v.x, v.y), pack2(v.z, v.w)};
    } else if (idx < NQKV + NW) {
        int i = idx - NQKV;
        float4 v = *(const float4*)(W1l + i);
        *(u32x2*)(w1bf + i) = (u32x2){pack2(v.x, v.y), pack2(v.z, v.w)};
    } else {
        int i = idx - NQKV - NW;
        float4 v = *(const float4*)(W2l + i);
        *(u32x2*)(w2bf + i) = (u32x2){pack2(v.x, v.y), pack2(v.z, v.w)};
    }
}

// ---------------- MFMA QKV: block = (128 token rows, head); swapped-operand epilogue -------
__global__ __launch_bounds__(256) void qkv_mfma(const ushort_t* __restrict__ xbf,
                                                const ushort_t* __restrict__ wqkv,
                                                const float* __restrict__ bq,
                                                const float* __restrict__ bk,
                                                const float* __restrict__ bv,
                                                ushort_t* __restrict__ qhb,
                                                ushort_t* __restrict__ khb,
                                                ushort_t* __restrict__ vtb) {
    __shared__ ushort_t As[128 * 64];
    int rt = blockIdx.x;
    int h = blockIdx.y;
    int t = threadIdx.x, lane = t & 63, wid = t >> 6;
    int wr = wid >> 1, wc = wid & 1;     // wave tile: 64 rows x 96 cols
    {
        int lr = t >> 3, lg = t & 7;
#pragma unroll
        for (int u = 0; u < 4; ++u) {
            int r = u * 32 + lr;
            int grow = rt * 128 + r;
            if (grow >= R_ROWS) grow = R_ROWS - 1;
            short8 a = *(const short8*)(xbf + (size_t)grow * 768 + h * 64 + lg * 8);
            *(short8*)&As[r * 64 + (lg ^ (r & 7)) * 8] = a;
        }
    }
    __syncthreads();
    int frow = lane & 15, g = lane >> 4;
    const ushort_t* wb = wqkv + (size_t)h * (192 * 64);
    f32x4 acc[4][6];
#pragma unroll
    for (int m = 0; m < 4; ++m)
#pragma unroll
        for (int n = 0; n < 6; ++n) acc[m][n] = (f32x4){0.f, 0.f, 0.f, 0.f};
#pragma unroll
    for (int kk = 0; kk < 2; ++kk) {
        short8 af[4], bfr[6];
#pragma unroll
        for (int m = 0; m < 4; ++m) {
            int r = wr * 64 + m * 16 + frow;
            af[m] = *(const short8*)&As[r * 64 + ((kk * 4 + g) ^ (r & 7)) * 8];
        }
#pragma unroll
        for (int n = 0; n < 6; ++n)
            bfr[n] = *(const short8*)(wb + (size_t)(wc * 96 + n * 16 + frow) * 64 + kk * 32 + g * 8);
#pragma unroll
        for (int m = 0; m < 4; ++m)
#pragma unroll
            for (int n = 0; n < 6; ++n)
                acc[m][n] = __builtin_amdgcn_mfma_f32_16x16x32_bf16(bfr[n], af[m], acc[m][n], 0, 0, 0);
    }
#pragma unroll
    for (int m = 0; m < 4; ++m) {
        int token = rt * 128 + wr * 64 + m * 16 + frow;
        if (token < R_ROWS) {
            unsigned nimg = (unsigned)token / 257u;
            unsigned s = (unsigned)token - nimg * 257u;
            size_t qk_base = ((size_t)(nimg * H_HEADS + h) * 257 + s) * 64;
            size_t v_base = (size_t)(nimg * H_HEADS + h) * (64 * SKV);
#pragma unroll
            for (int n = 0; n < 6; ++n) {
                int c = wc * 96 + n * 16 + g * 4;
                f32x4 a = acc[m][n];
                if (c < 64) {
                    const float4 bb = *(const float4*)(bq + h * 64 + c);
                    *(u32x2*)(qhb + qk_base + c) = (u32x2){
                        pack2((a[0] + bb.x) * 0.125f, (a[1] + bb.y) * 0.125f),
                        pack2((a[2] + bb.z) * 0.125f, (a[3] + bb.w) * 0.125f)};
                } else if (c < 128) {
                    const float4 bb = *(const float4*)(bk + h * 64 + (c - 64));
                    *(u32x2*)(khb + qk_base + (c - 64)) = (u32x2){
                        pack2(a[0] + bb.x, a[1] + bb.y), pack2(a[2] + bb.z, a[3] + bb.w)};
                } else {
                    const float4 bb = *(const float4*)(bv + h * 64 + (c - 128));
                    vtb[v_base + (size_t)(c - 128 + 0) * SKV + s] = f2bf(a[0] + bb.x);
                    vtb[v_base + (size_t)(c - 128 + 1) * SKV + s] = f2bf(a[1] + bb.y);
                    vtb[v_base + (size_t)(c - 128 + 2) * SKV + s] = f2bf(a[2] + bb.z);
                    vtb[v_base + (size_t)(c - 128 + 3) * SKV + s] = f2bf(a[3] + bb.w);
                }
            }
        }
    }
}

// ---------------- MFMA flash attention body: NST q-states per wave share K/V loads ---------
template <int NST>
__device__ __forceinline__ void attn_body(ushort_t* Pl,
                                          const ushort_t* __restrict__ qhp,
                                          const ushort_t* __restrict__ khp,
                                          const ushort_t* __restrict__ vp,
                                          float* __restrict__ tok,
                                          int n, int h, int base, int t) {
    int w = t >> 6, lane = t & 63;
    int lq = lane & 15, g = lane >> 4;
    const int xorm = (lq & 7) << 4;
    char* pw0 = (char*)(Pl + (size_t)w * 3 * 1024);

    short8 qf[NST][2];
    int qr0[NST];
    float m[NST], lsum[NST];
    f32x4 o[NST][4];
#pragma unroll
    for (int s = 0; s < NST; ++s) {
        int qrow = base + s * 64 + w * 16 + lq;
        qr0[s] = qrow;
        int qcl = qrow > 256 ? 256 : qrow;
#pragma unroll
        for (int kk = 0; kk < 2; ++kk)
            qf[s][kk] = *(const short8*)(qhp + (size_t)qcl * 64 + kk * 32 + g * 8);
        m[s] = -INFINITY; lsum[s] = 0.f;
#pragma unroll
        for (int dt = 0; dt < 4; ++dt) o[s][dt] = (f32x4){0.f, 0.f, 0.f, 0.f};
    }

    for (int kt = 0; kt < 5; ++kt) {
        short8 ah[4][2];
#pragma unroll
        for (int st = 0; st < 4; ++st) {
            int key = kt * 64 + st * 16 + lq;
            int kcl = key > 256 ? 256 : key;
            const ushort_t* krh = khp + (size_t)kcl * 64 + g * 8;
            ah[st][0] = *(const short8*)krh;
            ah[st][1] = *(const short8*)(krh + 32);
        }
        f32x4 c[NST][4];
#pragma unroll
        for (int s = 0; s < NST; ++s)
#pragma unroll
            for (int st = 0; st < 4; ++st) {
                c[s][st] = (f32x4){0.f, 0.f, 0.f, 0.f};
#pragma unroll
                for (int kk = 0; kk < 2; ++kk)
                    c[s][st] = __builtin_amdgcn_mfma_f32_16x16x32_bf16(ah[st][kk], qf[s][kk], c[s][st], 0, 0, 0);
            }
        float scale[NST];
        unsigned pw[NST][4][2];
#pragma unroll
        for (int s = 0; s < NST; ++s) {
            float tmax = -INFINITY;
#pragma unroll
            for (int st = 0; st < 4; ++st)
#pragma unroll
                for (int j = 0; j < 4; ++j) {
                    int key = kt * 64 + st * 16 + g * 4 + j;
                    float sv = (key <= 256) ? c[s][st][j] : -INFINITY;
                    c[s][st][j] = sv;
                    tmax = fmaxf(tmax, sv);
                }
            tmax = fmaxf(tmax, __shfl_xor(tmax, 16));
            tmax = fmaxf(tmax, __shfl_xor(tmax, 32));
            float mn = fmaxf(m[s], tmax);
            scale[s] = __expf(m[s] - mn);
            float psum = 0.f;
#pragma unroll
            for (int st = 0; st < 4; ++st) {
                float p0 = __expf(c[s][st][0] - mn), p1 = __expf(c[s][st][1] - mn);
                float p2 = __expf(c[s][st][2] - mn), p3 = __expf(c[s][st][3] - mn);
                psum += (p0 + p1) + (p2 + p3);
                pw[s][st][0] = pack2(p0, p1);
                pw[s][st][1] = pack2(p2, p3);
            }
            psum += __shfl_xor(psum, 16);
            psum += __shfl_xor(psum, 32);
            lsum[s] = lsum[s] * scale[s] + psum;
            m[s] = mn;
        }
#pragma unroll
        for (int s = 0; s < NST; ++s) {
            char* pwave = pw0 + s * 2048;
#pragma unroll
            for (int st = 0; st < 4; ++st) {
                int off = (lq * 128 + st * 32 + g * 8) ^ xorm;
                *(u32x2*)(pwave + off) = (u32x2){pw[s][st][0], pw[s][st][1]};
            }
#pragma unroll
            for (int dt = 0; dt < 4; ++dt) {
                o[s][dt][0] *= scale[s]; o[s][dt][1] *= scale[s];
                o[s][dt][2] *= scale[s]; o[s][dt][3] *= scale[s];
            }
        }
#pragma unroll
        for (int kk = 0; kk < 2; ++kk) {
            short8 pf[NST];
#pragma unroll
            for (int s = 0; s < NST; ++s) {
                int roff = (lq * 128 + kk * 64 + g * 16) ^ xorm;
                pf[s] = *(const short8*)(pw0 + s * 2048 + roff);
            }
#pragma unroll
            for (int dt = 0; dt < 4; ++dt) {
                short8 vf = *(const short8*)(vp + (size_t)(dt * 16 + lq) * SKV + kt * 64 + kk * 32 + g * 8);
#pragma unroll
                for (int s = 0; s < NST; ++s)
                    o[s][dt] = __builtin_amdgcn_mfma_f32_16x16x32_bf16(vf, pf[s], o[s][dt], 0, 0, 0);
            }
        }
    }
#pragma unroll
    for (int s = 0; s < NST; ++s) {
        if (qr0[s] < S_LEN) {
            float inv = 1.0f / lsum[s];
            float* trow = tok + ((size_t)n * S_LEN + qr0[s]) * 768 + h * 64 + g * 4;
#pragma unroll
            for (int dt = 0; dt < 4; ++dt) {
                float4 old = *(const float4*)(trow + dt * 16);
                old.x += o[s][dt][0] * inv;
                old.y += o[s][dt][1] * inv;
                old.z += o[s][dt][2] * inv;
                old.w += o[s][dt][3] * inv;
                *(float4*)(trow + dt * 16) = old;
            }
        }
    }
}

// merged: one 512-thread block per (n,h); waves 0-3 rows [0,128), waves 4-7 rows [128,257]
__global__ __launch_bounds__(512) void attn_fused(const ushort_t* __restrict__ qh,
                                                  const ushort_t* __restrict__ kh,
                                                  const ushort_t* __restrict__ vT,
                                                  float* __restrict__ tok) {
    __shared__ ushort_t Plds[8 * 3 * 1024];
    int nh = blockIdx.x;
    int h = nh % H_HEADS, n = nh / H_HEADS;
    const size_t hoff = ((size_t)n * H_HEADS + h) * (S_LEN * 64);
    const ushort_t* qhp = qh + hoff;
    const ushort_t* khp = kh + hoff;
    const ushort_t* vp  = vT + ((size_t)n * H_HEADS + h) * (64 * SKV);
    int t = threadIdx.x;
    if (t < 256) attn_body<2>(Plds, qhp, khp, vp, tok, n, h, 0, t);
    else         attn_body<3>(Plds + 4 * 3 * 1024, qhp, khp, vp, tok, n, h, 128, t - 256);
}

// ---------------- fast exact-erf GELU (A&S 7.1.26, abs err 1.5e-7) ----------------
__device__ __forceinline__ float gelu_fast(float x) {
    float s = fabsf(x) * 0.70710678118654752f;
    float t = 1.0f / (1.0f + 0.3275911f * s);
    float y = t * (0.254829592f + t * (-0.284496736f + t * (1.421413741f +
              t * (-1.453152027f + t * 1.061405429f))));
    float erfa = 1.0f - y * __expf(-s * s);
    float erfv = copysignf(erfa, x);
    return 0.5f * x * (1.0f + erfv);
}

// ---------------- bf16 MFMA GEMM (BK=64): round-12 2-phase, compile-time K ----------------
template <int MODE, int NT>
__global__ __launch_bounds__(256) void mfma_gemm(const ushort_t* __restrict__ A,
                                                 const ushort_t* __restrict__ B,
                                                 const float* __restrict__ bias,
                                                 void* __restrict__ Cv,
                                                 int lda, int ldb, int ldc, int nbn) {
    __shared__ ushort_t SMEM[4][8192];   // [0..1]: A slots, [2..3]: B slots
    int nwg = gridDim.x;
    int orig = blockIdx.x;
    int xcd = orig & 7, idx = orig >> 3;
    int q8 = nwg >> 3, r8 = nwg & 7;
    int cbase = (xcd < r8) ? xcd * (q8 + 1) : r8 * (q8 + 1) + (xcd - r8) * q8;
    int swb = cbase + idx;
    int bm = swb / nbn, bn = swb - bm * nbn;

    int t = threadIdx.x;
    int lane = t & 63, wid = t >> 6;
    int wr = wid >> 1, wc = wid & 1;         // wave tile: 64 x 64
    int srow = t >> 3;                       // 0..31
    int swzo = ((t & 7) ^ (srow & 7)) * 8;   // source pre-swizzle (matches read XOR)
    int wbase = (t & 192) * 8;               // wave-uniform LDS chunk base (shorts)
    int frow = lane & 15, g = lane >> 4;

    const ushort_t* pA[4];
    const ushort_t* pB[4];
#pragma unroll
    for (int u = 0; u < 4; ++u) {
        pA[u] = A + (size_t)(bm * 128 + u * 32 + srow) * lda + swzo;
        pB[u] = B + (size_t)(bn * 128 + u * 32 + srow) * ldb + swzo;
    }
    int offA[4][2], offB[4][2];
#pragma unroll
    for (int m = 0; m < 4; ++m)
#pragma unroll
        for (int kk = 0; kk < 2; ++kk) {
            int ra = wr * 64 + m * 16 + frow;
            offA[m][kk] = ra * 64 + ((kk * 4 + g) ^ (ra & 7)) * 8;
            int rb = wc * 64 + m * 16 + frow;
            offB[m][kk] = rb * 64 + ((kk * 4 + g) ^ (rb & 7)) * 8;
        }

    f32x4 acc[4][4];
#pragma unroll
    for (int m = 0; m < 4; ++m)
#pragma unroll
        for (int n = 0; n < 4; ++n) acc[m][n] = (f32x4){0.f, 0.f, 0.f, 0.f};

    auto STAGE = [&](int buf, int koff) {
#pragma unroll
        for (int u = 0; u < 4; ++u) {
            glds16(pA[u] + koff, &SMEM[buf][u * 2048 + wbase]);
            glds16(pB[u] + koff, &SMEM[2 + buf][u * 2048 + wbase]);
        }
    };
    auto COMPUTE = [&](int cur) {
#pragma unroll
        for (int kk = 0; kk < 2; ++kk) {
            short8 af[4], bf[4];
#pragma unroll
            for (int mi = 0; mi < 4; ++mi) af[mi] = *(const short8*)&SMEM[cur][offA[mi][kk]];
#pragma unroll
            for (int ni = 0; ni < 4; ++ni) bf[ni] = *(const short8*)&SMEM[2 + cur][offB[ni][kk]];
#pragma unroll
            for (int mi = 0; mi < 4; ++mi)
#pragma unroll
                for (int ni = 0; ni < 4; ++ni)
                    acc[mi][ni] = __builtin_amdgcn_mfma_f32_16x16x32_bf16(bf[ni], af[mi], acc[mi][ni], 0, 0, 0);
        }
    };

    STAGE(0, 0);
    asm volatile("s_waitcnt vmcnt(0)" ::: "memory");
    __builtin_amdgcn_s_barrier();

    constexpr int NOUT = NT / 12;
    for (int ot = 0; ot < NOUT - 1; ++ot) {
#pragma unroll
        for (int ii = 0; ii < 12; ++ii) {
            STAGE((ii + 1) & 1, (ii + 1) * 64);
            COMPUTE(ii & 1);
            asm volatile("s_waitcnt vmcnt(0) lgkmcnt(0)" ::: "memory");
            __builtin_amdgcn_s_barrier();
        }
#pragma unroll
        for (int u = 0; u < 4; ++u) { pA[u] += 12 * 64; pB[u] += 12 * 64; }
    }
#pragma unroll
    for (int ii = 0; ii < 12; ++ii) {
        if (ii + 1 < 12) STAGE((ii + 1) & 1, (ii + 1) * 64);
        COMPUTE(ii & 1);
        if (ii + 1 < 12) {
            asm volatile("s_waitcnt vmcnt(0) lgkmcnt(0)" ::: "memory");
            __builtin_amdgcn_s_barrier();
        }
    }

    int row0 = bm * 128 + wr * 64 + frow;
    int col0 = bn * 128 + wc * 64 + g * 4;
#pragma unroll
    for (int n = 0; n < 4; ++n) {
        int col = col0 + n * 16;
        float4 bb = {0.f, 0.f, 0.f, 0.f};
        if (bias) bb = *(const float4*)(bias + col);
#pragma unroll
        for (int mi = 0; mi < 4; ++mi) {
            int row = row0 + mi * 16;
            f32x4 a = acc[mi][n];
            float v0 = a[0] + bb.x, v1 = a[1] + bb.y, v2 = a[2] + bb.z, v3 = a[3] + bb.w;
            if (MODE == 0) {
                v0 = gelu_fast(v0); v1 = gelu_fast(v1); v2 = gelu_fast(v2); v3 = gelu_fast(v3);
                *(u32x2*)((ushort_t*)Cv + (size_t)row * ldc + col) =
                    (u32x2){pack2(v0, v1), pack2(v2, v3)};
            } else {
                float* cp = (float*)Cv + (size_t)row * ldc + col;
                float4 old = *(const float4*)cp;
                old.x += v0; old.y += v1; old.z += v2; old.w += v3;
                *(float4*)cp = old;
            }
        }
    }
}

// ---------------- bf16 MFMA GEMM (BK=32): 32KB LDS, FIXED conflict-free read swizzle -------
// Staged layout (dest-linear glds): slot s of row r holds source k-group s ^ ((r>>1)&3).
// Read therefore uses slot g ^ ((r>>1)&3)  [round 13 wrongly used g^(r&3): 4-way conflicts].
// Bank math: lanes sharing g span 16 rows; even rows (bank-base 0) map to 4 distinct slots,
// 2 lanes each -> 2-way = free; odd rows likewise on banks 16-31.
template <int MODE, int NT>
__global__ __launch_bounds__(256) void mfma_gemm32(const ushort_t* __restrict__ A,
                                                   const ushort_t* __restrict__ B,
                                                   const float* __restrict__ bias,
                                                   void* __restrict__ Cv,
                                                   int lda, int ldb, int ldc, int nbn) {
    __shared__ ushort_t SMEM[4][4096];   // [0..1]: A slots, [2..3]: B slots (32 KB)
    int nwg = gridDim.x;
    int orig = blockIdx.x;
    int xcd = orig & 7, idx = orig >> 3;
    int q8 = nwg >> 3, r8 = nwg & 7;
    int cbase = (xcd < r8) ? xcd * (q8 + 1) : r8 * (q8 + 1) + (xcd - r8) * q8;
    int swb = cbase + idx;
    int bm = swb / nbn, bn = swb - bm * nbn;

    int t = threadIdx.x;
    int lane = t & 63, wid = t >> 6;
    int wr = wid >> 1, wc = wid & 1;         // wave tile: 64 x 64
    int srow = t >> 2;                       // 0..63
    int swzo = ((t & 3) ^ ((t >> 3) & 3)) * 8;  // source pre-swizzle (= (l&3)^((r>>1)&3))
    int wbase = (t & 192) * 8;               // w*512 shorts (wave-uniform)
    int frow = lane & 15, g = lane >> 4;

    const ushort_t* pA[2];
    const ushort_t* pB[2];
#pragma unroll
    for (int u = 0; u < 2; ++u) {
        pA[u] = A + (size_t)(bm * 128 + u * 64 + srow) * lda + swzo;
        pB[u] = B + (size_t)(bn * 128 + u * 64 + srow) * ldb + swzo;
    }
    int offA[4], offB[4];
#pragma unroll
    for (int m = 0; m < 4; ++m) {
        int ra = wr * 64 + m * 16 + frow;
        offA[m] = ra * 32 + ((g ^ ((ra >> 1) & 3)) * 8);   // FIXED
        int rb = wc * 64 + m * 16 + frow;
        offB[m] = rb * 32 + ((g ^ ((rb >> 1) & 3)) * 8);   // FIXED
    }

    f32x4 acc[4][4];
#pragma unroll
    for (int m = 0; m < 4; ++m)
#pragma unroll
        for (int n = 0; n < 4; ++n) acc[m][n] = (f32x4){0.f, 0.f, 0.f, 0.f};

    auto STAGE = [&](int buf, int koff) {
#pragma unroll
        for (int u = 0; u < 2; ++u) {
            glds16(pA[u] + koff, &SMEM[buf][u * 2048 + wbase]);
            glds16(pB[u] + koff, &SMEM[2 + buf][u * 2048 + wbase]);
        }
    };
    auto COMPUTE = [&](int cur) {
        short8 af[4], bf[4];
#pragma unroll
        for (int mi = 0; mi < 4; ++mi) af[mi] = *(const short8*)&SMEM[cur][offA[mi]];
#pragma unroll
        for (int ni = 0; ni < 4; ++ni) bf[ni] = *(const short8*)&SMEM[2 + cur][offB[ni]];
#pragma unroll
        for (int mi = 0; mi < 4; ++mi)
#pragma unroll
            for (int ni = 0; ni < 4; ++ni)
                acc[mi][ni] = __builtin_amdgcn_mfma_f32_16x16x32_bf16(bf[ni], af[mi], acc[mi][ni], 0, 0, 0);
    };

    STAGE(0, 0);
    asm volatile("s_waitcnt vmcnt(0)" ::: "memory");
    __builtin_amdgcn_s_barrier();

    constexpr int NOUT = NT / 12;
    for (int ot = 0; ot < NOUT - 1; ++ot) {
#pragma unroll
        for (int ii = 0; ii < 12; ++ii) {
            STAGE((ii + 1) & 1, (ii + 1) * 32);
            COMPUTE(ii & 1);
            asm volatile("s_waitcnt vmcnt(0) lgkmcnt(0)" ::: "memory");
            __builtin_amdgcn_s_barrier();
        }
#pragma unroll
        for (int u = 0; u < 2; ++u) { pA[u] += 12 * 32; pB[u] += 12 * 32; }
    }
#pragma unroll
    for (int ii = 0; ii < 12; ++ii) {
        if (ii + 1 < 12) STAGE((ii + 1) & 1, (ii + 1) * 32);
        COMPUTE(ii & 1);
        if (ii + 1 < 12) {
            asm volatile("s_waitcnt vmcnt(0) lgkmcnt(0)" ::: "memory");
            __builtin_amdgcn_s_barrier();
        }
    }

    int row0 = bm * 128 + wr * 64 + frow;
    int col0 = bn * 128 + wc * 64 + g * 4;
#pragma unroll
    for (int n = 0; n < 4; ++n) {
        int col = col0 + n * 16;
        float4 bb = {0.f, 0.f, 0.f, 0.f};
        if (bias) bb = *(const float4*)(bias + col);
#pragma unroll
        for (int mi = 0; mi < 4; ++mi) {
            int row = row0 + mi * 16;
            f32x4 a = acc[mi][n];
            float v0 = a[0] + bb.x, v1 = a[1] + bb.y, v2 = a[2] + bb.z, v3 = a[3] + bb.w;
            if (MODE == 0) {
                v0 = gelu_fast(v0); v1 = gelu_fast(v1); v2 = gelu_fast(v2); v3 = gelu_fast(v3);
                *(u32x2*)((ushort_t*)Cv + (size_t)row * ldc + col) =
                    (u32x2){pack2(v0, v1), pack2(v2, v3)};
            } else {
                float* cp = (float*)Cv + (size_t)row * ldc + col;
                float4 old = *(const float4*)cp;
                old.x += v0; old.y += v1; old.z += v2; old.w += v3;
                *(float4*)cp = old;
            }
        }
    }
}

// ---------------- classifier head + softmax ----------------
__global__ __launch_bounds__(64) void head_kernel(const float* __restrict__ tok,
                                                  const float* __restrict__ Whead,
                                                  const float* __restrict__ bhead,
                                                  float* __restrict__ out) {
    int n = blockIdx.x;
    int t = threadIdx.x;
    __shared__ float logits[OUT_DIM];
    if (t < OUT_DIM) {
        float acc = bhead[t];
        const float* xr = tok + (size_t)n * S_LEN * 768;
        const float* w = Whead + t * 768;
        for (int d = 0; d < 768; ++d) acc += xr[d] * w[d];
        logits[t] = acc;
    }
    __syncthreads();
    if (t == 0) {
        float m = -INFINITY;
        for (int o = 0; o < OUT_DIM; ++o) m = fmaxf(m, logits[o]);
        float ssum = 0.f;
        float e[OUT_DIM];
        for (int o = 0; o < OUT_DIM; ++o) { e[o] = expf(logits[o] - m); ssum += e[o]; }
        float inv = 1.0f / ssum;
        for (int o = 0; o < OUT_DIM; ++o) out[n * OUT_DIM + o] = e[o] * inv;
    }
}

extern "C" void kernel_launch(void* const* d_in, const int* in_sizes, int n_in,
                              void* d_out, int out_size, void* d_ws, size_t ws_size,
                              hipStream_t stream) {
    const float* images = (const float*)d_in[0];
    const float* Wemb   = (const float*)d_in[1];
    const float* bemb   = (const float*)d_in[2];
    const float* cls    = (const float*)d_in[3];
    const float* Wq     = (const float*)d_in[4];
    const float* bq     = (const float*)d_in[5];
    const float* Wk     = (const float*)d_in[6];
    const float* bk     = (const float*)d_in[7];
    const float* Wv     = (const float*)d_in[8];
    const float* bv     = (const float*)d_in[9];
    const float* ln1_g  = (const float*)d_in[10];
    const float* ln1_b  = (const float*)d_in[11];
    const float* ln2_g  = (const float*)d_in[12];
    const float* ln2_b  = (const float*)d_in[13];
    const float* W1     = (const float*)d_in[14];
    const float* b1     = (const float*)d_in[15];
    const float* W2     = (const float*)d_in[16];
    const float* b2     = (const float*)d_in[17];
    const float* Whead  = (const float*)d_in[18];
    const float* bhead  = (const float*)d_in[19];
    float* out = (float*)d_out;

    const size_t TOKP = (size_t)R_PAD * D_MODEL;               // 12,681,216
    const size_t QKSZ = (size_t)N_IMG * H_HEADS * S_LEN * 64;  // 12,632,064
    const size_t VTSZ = (size_t)N_IMG * H_HEADS * 64 * SKV;    // 15,728,640
    const size_t WSZ  = (size_t)F_HID * D_MODEL;               // 2,359,296
    float* ws   = (float*)d_ws;
    float* pos  = ws;                                          // 197,376 f32
    float* tok  = pos + 197376;                                // TOKP f32
    ushort_t* xbf  = (ushort_t*)(tok + TOKP);                  // TOKP bf16
    ushort_t* qhb  = xbf + TOKP;                               // QKSZ
    ushort_t* khb  = qhb + QKSZ;                               // QKSZ
    ushort_t* vtb  = khb + QKSZ;                               // VTSZ
    ushort_t* wqkvbf = vtb + VTSZ;                             // 147,456
    ushort_t* w1bf = wqkvbf + H_HEADS * 192 * 64;              // full layer W1
    ushort_t* w2bf = w1bf + WSZ;                               // full layer W2
    ushort_t* hid_full = w2bf + WSZ;                           // R_PAD*F_HID bf16 (if ws allows)

    const size_t hid_bytes = (size_t)R_PAD * F_HID * 2;
    const size_t needed = ((char*)hid_full - (char*)d_ws) + hid_bytes;
    int nchunk = (ws_size >= needed) ? 1 : 2;
    ushort_t* hid = (nchunk == 1) ? hid_full : qhb;   // fallback: overlay q/k region

    pos_kernel<<<S_LEN, 256, 0, stream>>>(pos);
    embed_kernel<<<R_ROWS, 256, 0, stream>>>(images, Wemb, bemb, cls, pos, tok);

    for (int l = 0; l < L_LAYERS; ++l) {
        const size_t wqkv_off = (size_t)l * H_HEADS * 64 * 64;
        const size_t bqkv_off = (size_t)l * H_HEADS * 64;
        ln_kernel<<<R_ROWS / 4, 256, 0, stream>>>(tok, ln1_g + l * 768, ln1_b + l * 768, xbf);
        conv_layer<<<4752, 256, 0, stream>>>(
            Wq + wqkv_off, Wk + wqkv_off, Wv + wqkv_off,
            W1 + (size_t)l * WSZ, W2 + (size_t)l * WSZ,
            wqkvbf, w1bf, w2bf);
        qkv_mfma<<<dim3(R_PAD / 128, H_HEADS), 256, 0, stream>>>(
            xbf, wqkvbf, bq + bqkv_off, bk + bqkv_off, bv + bqkv_off, qhb, khb, vtb);
        attn_fused<<<N_IMG * H_HEADS, 512, 0, stream>>>(qhb, khb, vtb, tok);
        ln_kernel<<<R_ROWS / 4, 256, 0, stream>>>(tok, ln2_g + l * 768, ln2_b + l * 768, xbf);
        if (nchunk == 1) {
            mfma_gemm32<0, 24><<<(F_HID / 128) * (R_PAD / 128), 256, 0, stream>>>(
                xbf, w1bf, b1 + (size_t)l * F_HID, hid, 768, 768, F_HID, F_HID / 128);
            mfma_gemm<1, 48><<<(D_MODEL / 128) * (R_PAD / 128), 256, 0, stream>>>(
                hid, w2bf, b2 + (size_t)l * D_MODEL, tok, F_HID, F_HID, D_MODEL,
                D_MODEL / 128);
        } else {
            const int FC = F_HID / 2;
            for (int c = 0; c < 2; ++c) {
                int c0 = c * FC;
                mfma_gemm32<0, 24><<<(FC / 128) * (R_PAD / 128), 256, 0, stream>>>(
                    xbf, w1bf + (size_t)c0 * D_MODEL, b1 + (size_t)l * F_HID + c0, hid,
                    768, 768, FC, FC / 128);
                mfma_gemm<1, 24><<<(D_MODEL / 128) * (R_PAD / 128), 256, 0, stream>>>(
                    hid, w2bf + c0,
                    (c == 0) ? (b2 + (size_t)l * D_MODEL) : (const float*)nullptr,
                    tok, FC, F_HID, D_MODEL, D_MODEL / 128);
            }
        }
    }
    head_kernel<<<N_IMG, 64, 0, stream>>>(tok, Whead, bhead, out);
}

// Round 17
// 4604.298 us; speedup vs baseline: 1.0076x; 1.0076x over previous
//
#include <hip/hip_runtime.h>
#include <math.h>
#include <stdint.h>

#define N_IMG 64
#define S_LEN 257
#define D_MODEL 768
#define H_HEADS 12
#define L_LAYERS 12
#define F_HID 3072
#define OUT_DIM 10
#define R_ROWS (N_IMG * S_LEN)   // 16448
#define R_PAD 16512              // 129 * 128
#define SKV 320                  // padded key count for vT

typedef unsigned short ushort_t;
typedef __attribute__((ext_vector_type(4))) float f32x4;
typedef __attribute__((ext_vector_type(8))) short short8;
typedef __attribute__((ext_vector_type(2))) unsigned int u32x2;

__device__ __forceinline__ ushort_t f2bf(float x) {
    unsigned u = __float_as_uint(x);
    u += 0x7fffu + ((u >> 16) & 1u);
    return (ushort_t)(u >> 16);
}
__device__ __forceinline__ unsigned pack2(float a, float b) {
    return (unsigned)f2bf(a) | ((unsigned)f2bf(b) << 16);
}

// async global->LDS, 16B per lane; dest = wave-uniform base + lane*16
__device__ __forceinline__ void glds16(const ushort_t* g, const ushort_t* l) {
    __builtin_amdgcn_global_load_lds(
        (const __attribute__((address_space(1))) unsigned int*)(uintptr_t)g,
        (__attribute__((address_space(3))) unsigned int*)(uintptr_t)l,
        16, 0, 0);
}

// ---------------- positional embedding (double precision, matches numpy f64) ----------------
__global__ __launch_bounds__(256) void pos_kernel(float* __restrict__ pos) {
    int i = blockIdx.x;
    int t = threadIdx.x;
    for (int u = 0; u < 3; ++u) {
        int j = t + 256 * u;
        double e = (double)(j & ~1) / 768.0;
        double angle = (double)i * exp(-e * 9.210340371976184);
        double v = (j & 1) ? cos(angle) : sin(angle);
        pos[i * 768 + j] = (float)v;
    }
}

// ---------------- patch embed + cls + pos ----------------
__global__ __launch_bounds__(256) void embed_kernel(const float* __restrict__ images,
                                                    const float* __restrict__ Wemb,
                                                    const float* __restrict__ bemb,
                                                    const float* __restrict__ cls,
                                                    const float* __restrict__ pos,
                                                    float* __restrict__ tok) {
    int b = blockIdx.x;
    int n = b / S_LEN, s = b % S_LEN;
    int t = threadIdx.x;
    __shared__ float p[16];
    if (s > 0 && t < 16) p[t] = images[n * 4096 + (s - 1) * 16 + t];
    __syncthreads();
    for (int u = 0; u < 3; ++u) {
        int d = t + 256 * u;
        float acc;
        if (s == 0) {
            acc = cls[d];
        } else {
            acc = bemb[d];
            const float4* w = (const float4*)(Wemb + d * 16);
            float4 w0 = w[0], w1 = w[1], w2 = w[2], w3 = w[3];
            acc += p[0] * w0.x + p[1] * w0.y + p[2] * w0.z + p[3] * w0.w;
            acc += p[4] * w1.x + p[5] * w1.y + p[6] * w1.z + p[7] * w1.w;
            acc += p[8] * w2.x + p[9] * w2.y + p[10] * w2.z + p[11] * w2.w;
            acc += p[12] * w3.x + p[13] * w3.y + p[14] * w3.z + p[15] * w3.w;
        }
        tok[(size_t)b * 768 + d] = acc + pos[s * 768 + d];
    }
}

// ---------------- layernorm -> bf16 : one wave per row ----------------
__global__ __launch_bounds__(256) void ln_kernel(const float* __restrict__ x,
                                                 const float* __restrict__ g,
                                                 const float* __restrict__ b,
                                                 ushort_t* __restrict__ y) {
    int row = blockIdx.x * 4 + (threadIdx.x >> 6);
    int lane = threadIdx.x & 63;
    const float* xr = x + (size_t)row * 768 + lane * 4;
    float4 a0 = *(const float4*)xr;
    float4 a1 = *(const float4*)(xr + 256);
    float4 a2 = *(const float4*)(xr + 512);
    float s = (a0.x + a0.y + a0.z + a0.w) + (a1.x + a1.y + a1.z + a1.w) + (a2.x + a2.y + a2.z + a2.w);
    float sq = a0.x*a0.x + a0.y*a0.y + a0.z*a0.z + a0.w*a0.w
             + a1.x*a1.x + a1.y*a1.y + a1.z*a1.z + a1.w*a1.w
             + a2.x*a2.x + a2.y*a2.y + a2.z*a2.z + a2.w*a2.w;
    for (int o = 32; o; o >>= 1) {
        s += __shfl_xor(s, o);
        sq += __shfl_xor(sq, o);
    }
    float mu = s * (1.0f / 768.0f);
    float var = sq * (1.0f / 768.0f) - mu * mu;
    float rs = rsqrtf(var + 1e-5f);
    ushort_t* yr = y + (size_t)row * 768 + lane * 4;
#pragma unroll
    for (int i = 0; i < 3; ++i) {
        float4 av = (i == 0) ? a0 : (i == 1) ? a1 : a2;
        const float4 gg = *(const float4*)(g + lane * 4 + i * 256);
        const float4 bb = *(const float4*)(b + lane * 4 + i * 256);
        float o0 = (av.x - mu) * rs * gg.x + bb.x;
        float o1 = (av.y - mu) * rs * gg.y + bb.y;
        float o2 = (av.z - mu) * rs * gg.z + bb.z;
        float o3 = (av.w - mu) * rs * gg.w + bb.w;
        *(u32x2*)(yr + i * 256) = (u32x2){pack2(o0, o1), pack2(o2, o3)};
    }
}

// ---------------- per-layer weight conversion: wqkv pack + full W1 + full W2 ----------------
__global__ __launch_bounds__(256) void conv_layer(const float* __restrict__ Wq,
                                                  const float* __restrict__ Wk,
                                                  const float* __restrict__ Wv,
                                                  const float* __restrict__ W1l,
                                                  const float* __restrict__ W2l,
                                                  ushort_t* __restrict__ wqkvbf,
                                                  ushort_t* __restrict__ w1bf,
                                                  ushort_t* __restrict__ w2bf) {
    const int NQKV = H_HEADS * 192 * 64;       // 147456
    const int NW = F_HID * D_MODEL;            // 2359296
    int idx = (blockIdx.x * 256 + threadIdx.x) * 4;
    if (idx < NQKV) {
        int h = idx / (192 * 64);
        int rem = idx - h * 192 * 64;
        int o3 = rem >> 6, d = rem & 63;
        const float* src;
        int o;
        if (o3 < 64)       { src = Wq; o = o3; }
        else if (o3 < 128) { src = Wk; o = o3 - 64; }
        else               { src = Wv; o = o3 - 128; }
        float4 v = *(const float4*)(src + ((size_t)(h * 64 + o)) * 64 + d);
        *(u32x2*)(wqkvbf + idx) = (u32x2){pack2(v.x, v.y), pack2(v.z, v.w)};
    } else if (idx < NQKV + NW) {
        int i = idx - NQKV;
        float4 v = *(const float4*)(W1l + i);
        *(u32x2*)(w1bf + i) = (u32x2){pack2(v.x, v.y), pack2(v.z, v.w)};
    } else {
        int i = idx - NQKV - NW;
        float4 v = *(const float4*)(W2l + i);
        *(u32x2*)(w2bf + i) = (u32x2){pack2(v.x, v.y), pack2(v.z, v.w)};
    }
}

// ---------------- MFMA QKV: block = (128 token rows, head); swapped-operand epilogue -------
__global__ __launch_bounds__(256) void qkv_mfma(const ushort_t* __restrict__ xbf,
                                                const ushort_t* __restrict__ wqkv,
                                                const float* __restrict__ bq,
                                                const float* __restrict__ bk,
                                                const float* __restrict__ bv,
                                                ushort_t* __restrict__ qhb,
                                                ushort_t* __restrict__ khb,
                                                ushort_t* __restrict__ vtb) {
    __shared__ ushort_t As[128 * 64];
    int rt = blockIdx.x;
    int h = blockIdx.y;
    int t = threadIdx.x, lane = t & 63, wid = t >> 6;
    int wr = wid >> 1, wc = wid & 1;     // wave tile: 64 rows x 96 cols
    {
        int lr = t >> 3, lg = t & 7;
#pragma unroll
        for (int u = 0; u < 4; ++u) {
            int r = u * 32 + lr;
            int grow = rt * 128 + r;
            if (grow >= R_ROWS) grow = R_ROWS - 1;
            short8 a = *(const short8*)(xbf + (size_t)grow * 768 + h * 64 + lg * 8);
            *(short8*)&As[r * 64 + (lg ^ (r & 7)) * 8] = a;
        }
    }
    __syncthreads();
    int frow = lane & 15, g = lane >> 4;
    const ushort_t* wb = wqkv + (size_t)h * (192 * 64);
    f32x4 acc[4][6];
#pragma unroll
    for (int m = 0; m < 4; ++m)
#pragma unroll
        for (int n = 0; n < 6; ++n) acc[m][n] = (f32x4){0.f, 0.f, 0.f, 0.f};
#pragma unroll
    for (int kk = 0; kk < 2; ++kk) {
        short8 af[4], bfr[6];
#pragma unroll
        for (int m = 0; m < 4; ++m) {
            int r = wr * 64 + m * 16 + frow;
            af[m] = *(const short8*)&As[r * 64 + ((kk * 4 + g) ^ (r & 7)) * 8];
        }
#pragma unroll
        for (int n = 0; n < 6; ++n)
            bfr[n] = *(const short8*)(wb + (size_t)(wc * 96 + n * 16 + frow) * 64 + kk * 32 + g * 8);
#pragma unroll
        for (int m = 0; m < 4; ++m)
#pragma unroll
            for (int n = 0; n < 6; ++n)
                acc[m][n] = __builtin_amdgcn_mfma_f32_16x16x32_bf16(bfr[n], af[m], acc[m][n], 0, 0, 0);
    }
#pragma unroll
    for (int m = 0; m < 4; ++m) {
        int token = rt * 128 + wr * 64 + m * 16 + frow;
        if (token < R_ROWS) {
            unsigned nimg = (unsigned)token / 257u;
            unsigned s = (unsigned)token - nimg * 257u;
            size_t qk_base = ((size_t)(nimg * H_HEADS + h) * 257 + s) * 64;
            size_t v_base = (size_t)(nimg * H_HEADS + h) * (64 * SKV);
#pragma unroll
            for (int n = 0; n < 6; ++n) {
                int c = wc * 96 + n * 16 + g * 4;
                f32x4 a = acc[m][n];
                if (c < 64) {
                    const float4 bb = *(const float4*)(bq + h * 64 + c);
                    *(u32x2*)(qhb + qk_base + c) = (u32x2){
                        pack2((a[0] + bb.x) * 0.125f, (a[1] + bb.y) * 0.125f),
                        pack2((a[2] + bb.z) * 0.125f, (a[3] + bb.w) * 0.125f)};
                } else if (c < 128) {
                    const float4 bb = *(const float4*)(bk + h * 64 + (c - 64));
                    *(u32x2*)(khb + qk_base + (c - 64)) = (u32x2){
                        pack2(a[0] + bb.x, a[1] + bb.y), pack2(a[2] + bb.z, a[3] + bb.w)};
                } else {
                    const float4 bb = *(const float4*)(bv + h * 64 + (c - 128));
                    vtb[v_base + (size_t)(c - 128 + 0) * SKV + s] = f2bf(a[0] + bb.x);
                    vtb[v_base + (size_t)(c - 128 + 1) * SKV + s] = f2bf(a[1] + bb.y);
                    vtb[v_base + (size_t)(c - 128 + 2) * SKV + s] = f2bf(a[2] + bb.z);
                    vtb[v_base + (size_t)(c - 128 + 3) * SKV + s] = f2bf(a[3] + bb.w);
                }
            }
        }
    }
}

// ---------------- MFMA flash attention body: NST q-states per wave share K/V loads ---------
template <int NST>
__device__ __forceinline__ void attn_body(ushort_t* Pl,
                                          const ushort_t* __restrict__ qhp,
                                          const ushort_t* __restrict__ khp,
                                          const ushort_t* __restrict__ vp,
                                          float* __restrict__ tok,
                                          int n, int h, int base, int t) {
    int w = t >> 6, lane = t & 63;
    int lq = lane & 15, g = lane >> 4;
    const int xorm = (lq & 7) << 4;
    char* pw0 = (char*)(Pl + (size_t)w * 3 * 1024);

    short8 qf[NST][2];
    int qr0[NST];
    float m[NST], lsum[NST];
    f32x4 o[NST][4];
#pragma unroll
    for (int s = 0; s < NST; ++s) {
        int qrow = base + s * 64 + w * 16 + lq;
        qr0[s] = qrow;
        int qcl = qrow > 256 ? 256 : qrow;
#pragma unroll
        for (int kk = 0; kk < 2; ++kk)
            qf[s][kk] = *(const short8*)(qhp + (size_t)qcl * 64 + kk * 32 + g * 8);
        m[s] = -INFINITY; lsum[s] = 0.f;
#pragma unroll
        for (int dt = 0; dt < 4; ++dt) o[s][dt] = (f32x4){0.f, 0.f, 0.f, 0.f};
    }

    for (int kt = 0; kt < 5; ++kt) {
        short8 ah[4][2];
#pragma unroll
        for (int st = 0; st < 4; ++st) {
            int key = kt * 64 + st * 16 + lq;
            int kcl = key > 256 ? 256 : key;
            const ushort_t* krh = khp + (size_t)kcl * 64 + g * 8;
            ah[st][0] = *(const short8*)krh;
            ah[st][1] = *(const short8*)(krh + 32);
        }
        f32x4 c[NST][4];
#pragma unroll
        for (int s = 0; s < NST; ++s)
#pragma unroll
            for (int st = 0; st < 4; ++st) {
                c[s][st] = (f32x4){0.f, 0.f, 0.f, 0.f};
#pragma unroll
                for (int kk = 0; kk < 2; ++kk)
                    c[s][st] = __builtin_amdgcn_mfma_f32_16x16x32_bf16(ah[st][kk], qf[s][kk], c[s][st], 0, 0, 0);
            }
        float scale[NST];
        unsigned pw[NST][4][2];
#pragma unroll
        for (int s = 0; s < NST; ++s) {
            float tmax = -INFINITY;
#pragma unroll
            for (int st = 0; st < 4; ++st)
#pragma unroll
                for (int j = 0; j < 4; ++j) {
                    int key = kt * 64 + st * 16 + g * 4 + j;
                    float sv = (key <= 256) ? c[s][st][j] : -INFINITY;
                    c[s][st][j] = sv;
                    tmax = fmaxf(tmax, sv);
                }
            tmax = fmaxf(tmax, __shfl_xor(tmax, 16));
            tmax = fmaxf(tmax, __shfl_xor(tmax, 32));
            float mn = fmaxf(m[s], tmax);
            scale[s] = __expf(m[s] - mn);
            float psum = 0.f;
#pragma unroll
            for (int st = 0; st < 4; ++st) {
                float p0 = __expf(c[s][st][0] - mn), p1 = __expf(c[s][st][1] - mn);
                float p2 = __expf(c[s][st][2] - mn), p3 = __expf(c[s][st][3] - mn);
                psum += (p0 + p1) + (p2 + p3);
                pw[s][st][0] = pack2(p0, p1);
                pw[s][st][1] = pack2(p2, p3);
            }
            psum += __shfl_xor(psum, 16);
            psum += __shfl_xor(psum, 32);
            lsum[s] = lsum[s] * scale[s] + psum;
            m[s] = mn;
        }
#pragma unroll
        for (int s = 0; s < NST; ++s) {
            char* pwave = pw0 + s * 2048;
#pragma unroll
            for (int st = 0; st < 4; ++st) {
                int off = (lq * 128 + st * 32 + g * 8) ^ xorm;
                *(u32x2*)(pwave + off) = (u32x2){pw[s][st][0], pw[s][st][1]};
            }
#pragma unroll
            for (int dt = 0; dt < 4; ++dt) {
                o[s][dt][0] *= scale[s]; o[s][dt][1] *= scale[s];
                o[s][dt][2] *= scale[s]; o[s][dt][3] *= scale[s];
            }
        }
#pragma unroll
        for (int kk = 0; kk < 2; ++kk) {
            short8 pf[NST];
#pragma unroll
            for (int s = 0; s < NST; ++s) {
                int roff = (lq * 128 + kk * 64 + g * 16) ^ xorm;
                pf[s] = *(const short8*)(pw0 + s * 2048 + roff);
            }
#pragma unroll
            for (int dt = 0; dt < 4; ++dt) {
                short8 vf = *(const short8*)(vp + (size_t)(dt * 16 + lq) * SKV + kt * 64 + kk * 32 + g * 8);
#pragma unroll
                for (int s = 0; s < NST; ++s)
                    o[s][dt] = __builtin_amdgcn_mfma_f32_16x16x32_bf16(vf, pf[s], o[s][dt], 0, 0, 0);
            }
        }
    }
#pragma unroll
    for (int s = 0; s < NST; ++s) {
        if (qr0[s] < S_LEN) {
            float inv = 1.0f / lsum[s];
            float* trow = tok + ((size_t)n * S_LEN + qr0[s]) * 768 + h * 64 + g * 4;
#pragma unroll
            for (int dt = 0; dt < 4; ++dt) {
                float4 old = *(const float4*)(trow + dt * 16);
                old.x += o[s][dt][0] * inv;
                old.y += o[s][dt][1] * inv;
                old.z += o[s][dt][2] * inv;
                old.w += o[s][dt][3] * inv;
                *(float4*)(trow + dt * 16) = old;
            }
        }
    }
}

// merged: one 512-thread block per (n,h); waves 0-3 do rows [0,128) (NST=2),
// waves 4-7 do rows [128,257] (NST=3). Both halves stream the SAME K/V tiles ->
// co-location makes the second reader hit L1/L2. Per-wave-private LDS, no barriers.
__global__ __launch_bounds__(512) void attn_fused(const ushort_t* __restrict__ qh,
                                                  const ushort_t* __restrict__ kh,
                                                  const ushort_t* __restrict__ vT,
                                                  float* __restrict__ tok) {
    __shared__ ushort_t Plds[8 * 3 * 1024];
    int nh = blockIdx.x;
    int h = nh % H_HEADS, n = nh / H_HEADS;
    const size_t hoff = ((size_t)n * H_HEADS + h) * (S_LEN * 64);
    const ushort_t* qhp = qh + hoff;
    const ushort_t* khp = kh + hoff;
    const ushort_t* vp  = vT + ((size_t)n * H_HEADS + h) * (64 * SKV);
    int t = threadIdx.x;
    if (t < 256) attn_body<2>(Plds, qhp, khp, vp, tok, n, h, 0, t);
    else         attn_body<3>(Plds + 4 * 3 * 1024, qhp, khp, vp, tok, n, h, 128, t - 256);
}

// ---------------- fast exact-erf GELU (A&S 7.1.26, abs err 1.5e-7) ----------------
__device__ __forceinline__ float gelu_fast(float x) {
    float s = fabsf(x) * 0.70710678118654752f;
    float t = 1.0f / (1.0f + 0.3275911f * s);
    float y = t * (0.254829592f + t * (-0.284496736f + t * (1.421413741f +
              t * (-1.453152027f + t * 1.061405429f))));
    float erfa = 1.0f - y * __expf(-s * s);
    float erfv = copysignf(erfa, x);
    return 0.5f * x * (1.0f + erfv);
}

// ---------------- bf16 MFMA GEMM (BK=64): proven best — 2-phase, compile-time K ------------
// 128x128 tile, 4 waves, A+B double-buffered in 64KB LDS (2 blocks/CU), imm-folded
// addressing via template NT + unroll-by-12. MODE 0: bias+gelu->bf16; MODE 1: +bias,
// accumulate fp32 into residual.
template <int MODE, int NT>
__global__ __launch_bounds__(256) void mfma_gemm(const ushort_t* __restrict__ A,
                                                 const ushort_t* __restrict__ B,
                                                 const float* __restrict__ bias,
                                                 void* __restrict__ Cv,
                                                 int lda, int ldb, int ldc, int nbn) {
    __shared__ ushort_t SMEM[4][8192];   // [0..1]: A slots, [2..3]: B slots
    int nwg = gridDim.x;
    int orig = blockIdx.x;
    int xcd = orig & 7, idx = orig >> 3;
    int q8 = nwg >> 3, r8 = nwg & 7;
    int cbase = (xcd < r8) ? xcd * (q8 + 1) : r8 * (q8 + 1) + (xcd - r8) * q8;
    int swb = cbase + idx;
    int bm = swb / nbn, bn = swb - bm * nbn;

    int t = threadIdx.x;
    int lane = t & 63, wid = t >> 6;
    int wr = wid >> 1, wc = wid & 1;         // wave tile: 64 x 64
    int srow = t >> 3;                       // 0..31
    int swzo = ((t & 7) ^ (srow & 7)) * 8;   // source pre-swizzle (matches read XOR)
    int wbase = (t & 192) * 8;               // wave-uniform LDS chunk base (shorts)
    int frow = lane & 15, g = lane >> 4;

    const ushort_t* pA[4];
    const ushort_t* pB[4];
#pragma unroll
    for (int u = 0; u < 4; ++u) {
        pA[u] = A + (size_t)(bm * 128 + u * 32 + srow) * lda + swzo;
        pB[u] = B + (size_t)(bn * 128 + u * 32 + srow) * ldb + swzo;
    }
    int offA[4][2], offB[4][2];
#pragma unroll
    for (int m = 0; m < 4; ++m)
#pragma unroll
        for (int kk = 0; kk < 2; ++kk) {
            int ra = wr * 64 + m * 16 + frow;
            offA[m][kk] = ra * 64 + ((kk * 4 + g) ^ (ra & 7)) * 8;
            int rb = wc * 64 + m * 16 + frow;
            offB[m][kk] = rb * 64 + ((kk * 4 + g) ^ (rb & 7)) * 8;
        }

    f32x4 acc[4][4];
#pragma unroll
    for (int m = 0; m < 4; ++m)
#pragma unroll
        for (int n = 0; n < 4; ++n) acc[m][n] = (f32x4){0.f, 0.f, 0.f, 0.f};

    auto STAGE = [&](int buf, int koff) {
#pragma unroll
        for (int u = 0; u < 4; ++u) {
            glds16(pA[u] + koff, &SMEM[buf][u * 2048 + wbase]);
            glds16(pB[u] + koff, &SMEM[2 + buf][u * 2048 + wbase]);
        }
    };
    auto COMPUTE = [&](int cur) {
#pragma unroll
        for (int kk = 0; kk < 2; ++kk) {
            short8 af[4], bf[4];
#pragma unroll
            for (int mi = 0; mi < 4; ++mi) af[mi] = *(const short8*)&SMEM[cur][offA[mi][kk]];
#pragma unroll
            for (int ni = 0; ni < 4; ++ni) bf[ni] = *(const short8*)&SMEM[2 + cur][offB[ni][kk]];
            // swapped: C[row=A-row(frow)][col=B-row(g*4+j)]
#pragma unroll
            for (int mi = 0; mi < 4; ++mi)
#pragma unroll
                for (int ni = 0; ni < 4; ++ni)
                    acc[mi][ni] = __builtin_amdgcn_mfma_f32_16x16x32_bf16(bf[ni], af[mi], acc[mi][ni], 0, 0, 0);
        }
    };

    STAGE(0, 0);
    asm volatile("s_waitcnt vmcnt(0)" ::: "memory");
    __builtin_amdgcn_s_barrier();

    constexpr int NOUT = NT / 12;
    for (int ot = 0; ot < NOUT - 1; ++ot) {
#pragma unroll
        for (int ii = 0; ii < 12; ++ii) {
            STAGE((ii + 1) & 1, (ii + 1) * 64);
            COMPUTE(ii & 1);
            asm volatile("s_waitcnt vmcnt(0) lgkmcnt(0)" ::: "memory");
            __builtin_amdgcn_s_barrier();
        }
#pragma unroll
        for (int u = 0; u < 4; ++u) { pA[u] += 12 * 64; pB[u] += 12 * 64; }
    }
#pragma unroll
    for (int ii = 0; ii < 12; ++ii) {
        if (ii + 1 < 12) STAGE((ii + 1) & 1, (ii + 1) * 64);
        COMPUTE(ii & 1);
        if (ii + 1 < 12) {
            asm volatile("s_waitcnt vmcnt(0) lgkmcnt(0)" ::: "memory");
            __builtin_amdgcn_s_barrier();
        }
    }

    int row0 = bm * 128 + wr * 64 + frow;
    int col0 = bn * 128 + wc * 64 + g * 4;
#pragma unroll
    for (int n = 0; n < 4; ++n) {
        int col = col0 + n * 16;
        float4 bb = {0.f, 0.f, 0.f, 0.f};
        if (bias) bb = *(const float4*)(bias + col);
#pragma unroll
        for (int mi = 0; mi < 4; ++mi) {
            int row = row0 + mi * 16;
            f32x4 a = acc[mi][n];
            float v0 = a[0] + bb.x, v1 = a[1] + bb.y, v2 = a[2] + bb.z, v3 = a[3] + bb.w;
            if (MODE == 0) {
                v0 = gelu_fast(v0); v1 = gelu_fast(v1); v2 = gelu_fast(v2); v3 = gelu_fast(v3);
                *(u32x2*)((ushort_t*)Cv + (size_t)row * ldc + col) =
                    (u32x2){pack2(v0, v1), pack2(v2, v3)};
            } else {
                float* cp = (float*)Cv + (size_t)row * ldc + col;
                float4 old = *(const float4*)cp;
                old.x += v0; old.y += v1; old.z += v2; old.w += v3;
                *(float4*)cp = old;
            }
        }
    }
}

// ---------------- classifier head + softmax ----------------
__global__ __launch_bounds__(64) void head_kernel(const float* __restrict__ tok,
                                                  const float* __restrict__ Whead,
                                                  const float* __restrict__ bhead,
                                                  float* __restrict__ out) {
    int n = blockIdx.x;
    int t = threadIdx.x;
    __shared__ float logits[OUT_DIM];
    if (t < OUT_DIM) {
        float acc = bhead[t];
        const float* xr = tok + (size_t)n * S_LEN * 768;
        const float* w = Whead + t * 768;
        for (int d = 0; d < 768; ++d) acc += xr[d] * w[d];
        logits[t] = acc;
    }
    __syncthreads();
    if (t == 0) {
        float m = -INFINITY;
        for (int o = 0; o < OUT_DIM; ++o) m = fmaxf(m, logits[o]);
        float ssum = 0.f;
        float e[OUT_DIM];
        for (int o = 0; o < OUT_DIM; ++o) { e[o] = expf(logits[o] - m); ssum += e[o]; }
        float inv = 1.0f / ssum;
        for (int o = 0; o < OUT_DIM; ++o) out[n * OUT_DIM + o] = e[o] * inv;
    }
}

extern "C" void kernel_launch(void* const* d_in, const int* in_sizes, int n_in,
                              void* d_out, int out_size, void* d_ws, size_t ws_size,
                              hipStream_t stream) {
    const float* images = (const float*)d_in[0];
    const float* Wemb   = (const float*)d_in[1];
    const float* bemb   = (const float*)d_in[2];
    const float* cls    = (const float*)d_in[3];
    const float* Wq     = (const float*)d_in[4];
    const float* bq     = (const float*)d_in[5];
    const float* Wk     = (const float*)d_in[6];
    const float* bk     = (const float*)d_in[7];
    const float* Wv     = (const float*)d_in[8];
    const float* bv     = (const float*)d_in[9];
    const float* ln1_g  = (const float*)d_in[10];
    const float* ln1_b  = (const float*)d_in[11];
    const float* ln2_g  = (const float*)d_in[12];
    const float* ln2_b  = (const float*)d_in[13];
    const float* W1     = (const float*)d_in[14];
    const float* b1     = (const float*)d_in[15];
    const float* W2     = (const float*)d_in[16];
    const float* b2     = (const float*)d_in[17];
    const float* Whead  = (const float*)d_in[18];
    const float* bhead  = (const float*)d_in[19];
    float* out = (float*)d_out;

    const size_t TOKP = (size_t)R_PAD * D_MODEL;               // 12,681,216
    const size_t QKSZ = (size_t)N_IMG * H_HEADS * S_LEN * 64;  // 12,632,064
    const size_t VTSZ = (size_t)N_IMG * H_HEADS * 64 * SKV;    // 15,728,640
    const size_t WSZ  = (size_t)F_HID * D_MODEL;               // 2,359,296
    float* ws   = (float*)d_ws;
    float* pos  = ws;                                          // 197,376 f32
    float* tok  = pos + 197376;                                // TOKP f32
    ushort_t* xbf  = (ushort_t*)(tok + TOKP);                  // TOKP bf16
    ushort_t* qhb  = xbf + TOKP;                               // QKSZ
    ushort_t* khb  = qhb + QKSZ;                               // QKSZ
    ushort_t* vtb  = khb + QKSZ;                               // VTSZ
    ushort_t* wqkvbf = vtb + VTSZ;                             // 147,456
    ushort_t* w1bf = wqkvbf + H_HEADS * 192 * 64;              // full layer W1
    ushort_t* w2bf = w1bf + WSZ;                               // full layer W2
    ushort_t* hid_full = w2bf + WSZ;                           // R_PAD*F_HID bf16 (if ws allows)

    const size_t hid_bytes = (size_t)R_PAD * F_HID * 2;
    const size_t needed = ((char*)hid_full - (char*)d_ws) + hid_bytes;
    int nchunk = (ws_size >= needed) ? 1 : 2;
    ushort_t* hid = (nchunk == 1) ? hid_full : qhb;   // fallback: overlay q/k region

    pos_kernel<<<S_LEN, 256, 0, stream>>>(pos);
    embed_kernel<<<R_ROWS, 256, 0, stream>>>(images, Wemb, bemb, cls, pos, tok);

    for (int l = 0; l < L_LAYERS; ++l) {
        const size_t wqkv_off = (size_t)l * H_HEADS * 64 * 64;
        const size_t bqkv_off = (size_t)l * H_HEADS * 64;
        ln_kernel<<<R_ROWS / 4, 256, 0, stream>>>(tok, ln1_g + l * 768, ln1_b + l * 768, xbf);
        conv_layer<<<4752, 256, 0, stream>>>(
            Wq + wqkv_off, Wk + wqkv_off, Wv + wqkv_off,
            W1 + (size_t)l * WSZ, W2 + (size_t)l * WSZ,
            wqkvbf, w1bf, w2bf);
        qkv_mfma<<<dim3(R_PAD / 128, H_HEADS), 256, 0, stream>>>(
            xbf, wqkvbf, bq + bqkv_off, bk + bqkv_off, bv + bqkv_off, qhb, khb, vtb);
        attn_fused<<<N_IMG * H_HEADS, 512, 0, stream>>>(qhb, khb, vtb, tok);
        ln_kernel<<<R_ROWS / 4, 256, 0, stream>>>(tok, ln2_g + l * 768, ln2_b + l * 768, xbf);
        if (nchunk == 1) {
            mfma_gemm<0, 12><<<(F_HID / 128) * (R_PAD / 128), 256, 0, stream>>>(
                xbf, w1bf, b1 + (size_t)l * F_HID, hid, 768, 768, F_HID, F_HID / 128);
            mfma_gemm<1, 48><<<(D_MODEL / 128) * (R_PAD / 128), 256, 0, stream>>>(
                hid, w2bf, b2 + (size_t)l * D_MODEL, tok, F_HID, F_HID, D_MODEL,
                D_MODEL / 128);
        } else {
            const int FC = F_HID / 2;
            for (int c = 0; c < 2; ++c) {
                int c0 = c * FC;
                mfma_gemm<0, 12><<<(FC / 128) * (R_PAD / 128), 256, 0, stream>>>(
                    xbf, w1bf + (size_t)c0 * D_MODEL, b1 + (size_t)l * F_HID + c0, hid,
                    768, 768, FC, FC / 128);
                mfma_gemm<1, 24><<<(D_MODEL / 128) * (R_PAD / 128), 256, 0, stream>>>(
                    hid, w2bf + c0,
                    (c == 0) ? (b2 + (size_t)l * D_MODEL) : (const float*)nullptr,
                    tok, FC, F_HID, D_MODEL, D_MODEL / 128);
            }
        }
    }
    head_kernel<<<N_IMG, 64, 0, stream>>>(tok, Whead, bhead, out);
}

// Round 18
// 4466.771 us; speedup vs baseline: 1.0386x; 1.0308x over previous
//
#include <hip/hip_runtime.h>
#include <math.h>
#include <stdint.h>

#define N_IMG 64
#define S_LEN 257
#define D_MODEL 768
#define H_HEADS 12
#define L_LAYERS 12
#define F_HID 3072
#define OUT_DIM 10
#define R_ROWS (N_IMG * S_LEN)   // 16448
#define R_PAD 16512              // 129 * 128
#define SKV 320                  // padded key count for vT

typedef unsigned short ushort_t;
typedef __attribute__((ext_vector_type(4))) float f32x4;
typedef __attribute__((ext_vector_type(8))) short short8;
typedef __attribute__((ext_vector_type(2))) unsigned int u32x2;

__device__ __forceinline__ ushort_t f2bf(float x) {
    unsigned u = __float_as_uint(x);
    u += 0x7fffu + ((u >> 16) & 1u);
    return (ushort_t)(u >> 16);
}
__device__ __forceinline__ unsigned pack2(float a, float b) {
    return (unsigned)f2bf(a) | ((unsigned)f2bf(b) << 16);
}

// async global->LDS, 16B per lane; dest = wave-uniform base + lane*16
__device__ __forceinline__ void glds16(const ushort_t* g, const ushort_t* l) {
    __builtin_amdgcn_global_load_lds(
        (const __attribute__((address_space(1))) unsigned int*)(uintptr_t)g,
        (__attribute__((address_space(3))) unsigned int*)(uintptr_t)l,
        16, 0, 0);
}

// ---------------- positional embedding (double precision, matches numpy f64) ----------------
__global__ __launch_bounds__(256) void pos_kernel(float* __restrict__ pos) {
    int i = blockIdx.x;
    int t = threadIdx.x;
    for (int u = 0; u < 3; ++u) {
        int j = t + 256 * u;
        double e = (double)(j & ~1) / 768.0;
        double angle = (double)i * exp(-e * 9.210340371976184);
        double v = (j & 1) ? cos(angle) : sin(angle);
        pos[i * 768 + j] = (float)v;
    }
}

// ---------------- patch embed + cls + pos ----------------
__global__ __launch_bounds__(256) void embed_kernel(const float* __restrict__ images,
                                                    const float* __restrict__ Wemb,
                                                    const float* __restrict__ bemb,
                                                    const float* __restrict__ cls,
                                                    const float* __restrict__ pos,
                                                    float* __restrict__ tok) {
    int b = blockIdx.x;
    int n = b / S_LEN, s = b % S_LEN;
    int t = threadIdx.x;
    __shared__ float p[16];
    if (s > 0 && t < 16) p[t] = images[n * 4096 + (s - 1) * 16 + t];
    __syncthreads();
    for (int u = 0; u < 3; ++u) {
        int d = t + 256 * u;
        float acc;
        if (s == 0) {
            acc = cls[d];
        } else {
            acc = bemb[d];
            const float4* w = (const float4*)(Wemb + d * 16);
            float4 w0 = w[0], w1 = w[1], w2 = w[2], w3 = w[3];
            acc += p[0] * w0.x + p[1] * w0.y + p[2] * w0.z + p[3] * w0.w;
            acc += p[4] * w1.x + p[5] * w1.y + p[6] * w1.z + p[7] * w1.w;
            acc += p[8] * w2.x + p[9] * w2.y + p[10] * w2.z + p[11] * w2.w;
            acc += p[12] * w3.x + p[13] * w3.y + p[14] * w3.z + p[15] * w3.w;
        }
        tok[(size_t)b * 768 + d] = acc + pos[s * 768 + d];
    }
}

// ---------------- layernorm -> bf16 : one wave per row ----------------
__global__ __launch_bounds__(256) void ln_kernel(const float* __restrict__ x,
                                                 const float* __restrict__ g,
                                                 const float* __restrict__ b,
                                                 ushort_t* __restrict__ y) {
    int row = blockIdx.x * 4 + (threadIdx.x >> 6);
    int lane = threadIdx.x & 63;
    const float* xr = x + (size_t)row * 768 + lane * 4;
    float4 a0 = *(const float4*)xr;
    float4 a1 = *(const float4*)(xr + 256);
    float4 a2 = *(const float4*)(xr + 512);
    float s = (a0.x + a0.y + a0.z + a0.w) + (a1.x + a1.y + a1.z + a1.w) + (a2.x + a2.y + a2.z + a2.w);
    float sq = a0.x*a0.x + a0.y*a0.y + a0.z*a0.z + a0.w*a0.w
             + a1.x*a1.x + a1.y*a1.y + a1.z*a1.z + a1.w*a1.w
             + a2.x*a2.x + a2.y*a2.y + a2.z*a2.z + a2.w*a2.w;
    for (int o = 32; o; o >>= 1) {
        s += __shfl_xor(s, o);
        sq += __shfl_xor(sq, o);
    }
    float mu = s * (1.0f / 768.0f);
    float var = sq * (1.0f / 768.0f) - mu * mu;
    float rs = rsqrtf(var + 1e-5f);
    ushort_t* yr = y + (size_t)row * 768 + lane * 4;
#pragma unroll
    for (int i = 0; i < 3; ++i) {
        float4 av = (i == 0) ? a0 : (i == 1) ? a1 : a2;
        const float4 gg = *(const float4*)(g + lane * 4 + i * 256);
        const float4 bb = *(const float4*)(b + lane * 4 + i * 256);
        float o0 = (av.x - mu) * rs * gg.x + bb.x;
        float o1 = (av.y - mu) * rs * gg.y + bb.y;
        float o2 = (av.z - mu) * rs * gg.z + bb.z;
        float o3 = (av.w - mu) * rs * gg.w + bb.w;
        *(u32x2*)(yr + i * 256) = (u32x2){pack2(o0, o1), pack2(o2, o3)};
    }
}

// ---------------- per-layer weight conversion: wqkv pack + full W1 + full W2 ----------------
__global__ __launch_bounds__(256) void conv_layer(const float* __restrict__ Wq,
                                                  const float* __restrict__ Wk,
                                                  const float* __restrict__ Wv,
                                                  const float* __restrict__ W1l,
                                                  const float* __restrict__ W2l,
                                                  ushort_t* __restrict__ wqkvbf,
                                                  ushort_t* __restrict__ w1bf,
                                                  ushort_t* __restrict__ w2bf) {
    const int NQKV = H_HEADS * 192 * 64;       // 147456
    const int NW = F_HID * D_MODEL;            // 2359296
    int idx = (blockIdx.x * 256 + threadIdx.x) * 4;
    if (idx < NQKV) {
        int h = idx / (192 * 64);
        int rem = idx - h * 192 * 64;
        int o3 = rem >> 6, d = rem & 63;
        const float* src;
        int o;
        if (o3 < 64)       { src = Wq; o = o3; }
        else if (o3 < 128) { src = Wk; o = o3 - 64; }
        else               { src = Wv; o = o3 - 128; }
        float4 v = *(const float4*)(src + ((size_t)(h * 64 + o)) * 64 + d);
        *(u32x2*)(wqkvbf + idx) = (u32x2){pack2(v.x, v.y), pack2(v.z, v.w)};
    } else if (idx < NQKV + NW) {
        int i = idx - NQKV;
        float4 v = *(const float4*)(W1l + i);
        *(u32x2*)(w1bf + i) = (u32x2){pack2(v.x, v.y), pack2(v.z, v.w)};
    } else {
        int i = idx - NQKV - NW;
        float4 v = *(const float4*)(W2l + i);
        *(u32x2*)(w2bf + i) = (u32x2){pack2(v.x, v.y), pack2(v.z, v.w)};
    }
}

// ---------------- MFMA QKV: block = (128 token rows, head); swapped-operand epilogue -------
__global__ __launch_bounds__(256) void qkv_mfma(const ushort_t* __restrict__ xbf,
                                                const ushort_t* __restrict__ wqkv,
                                                const float* __restrict__ bq,
                                                const float* __restrict__ bk,
                                                const float* __restrict__ bv,
                                                ushort_t* __restrict__ qhb,
                                                ushort_t* __restrict__ khb,
                                                ushort_t* __restrict__ vtb) {
    __shared__ ushort_t As[128 * 64];
    int rt = blockIdx.x;
    int h = blockIdx.y;
    int t = threadIdx.x, lane = t & 63, wid = t >> 6;
    int wr = wid >> 1, wc = wid & 1;     // wave tile: 64 rows x 96 cols
    {
        int lr = t >> 3, lg = t & 7;
#pragma unroll
        for (int u = 0; u < 4; ++u) {
            int r = u * 32 + lr;
            int grow = rt * 128 + r;
            if (grow >= R_ROWS) grow = R_ROWS - 1;
            short8 a = *(const short8*)(xbf + (size_t)grow * 768 + h * 64 + lg * 8);
            *(short8*)&As[r * 64 + (lg ^ (r & 7)) * 8] = a;
        }
    }
    __syncthreads();
    int frow = lane & 15, g = lane >> 4;
    const ushort_t* wb = wqkv + (size_t)h * (192 * 64);
    f32x4 acc[4][6];
#pragma unroll
    for (int m = 0; m < 4; ++m)
#pragma unroll
        for (int n = 0; n < 6; ++n) acc[m][n] = (f32x4){0.f, 0.f, 0.f, 0.f};
#pragma unroll
    for (int kk = 0; kk < 2; ++kk) {
        short8 af[4], bfr[6];
#pragma unroll
        for (int m = 0; m < 4; ++m) {
            int r = wr * 64 + m * 16 + frow;
            af[m] = *(const short8*)&As[r * 64 + ((kk * 4 + g) ^ (r & 7)) * 8];
        }
#pragma unroll
        for (int n = 0; n < 6; ++n)
            bfr[n] = *(const short8*)(wb + (size_t)(wc * 96 + n * 16 + frow) * 64 + kk * 32 + g * 8);
#pragma unroll
        for (int m = 0; m < 4; ++m)
#pragma unroll
            for (int n = 0; n < 6; ++n)
                acc[m][n] = __builtin_amdgcn_mfma_f32_16x16x32_bf16(bfr[n], af[m], acc[m][n], 0, 0, 0);
    }
#pragma unroll
    for (int m = 0; m < 4; ++m) {
        int token = rt * 128 + wr * 64 + m * 16 + frow;
        if (token < R_ROWS) {
            unsigned nimg = (unsigned)token / 257u;
            unsigned s = (unsigned)token - nimg * 257u;
            size_t qk_base = ((size_t)(nimg * H_HEADS + h) * 257 + s) * 64;
            size_t v_base = (size_t)(nimg * H_HEADS + h) * (64 * SKV);
#pragma unroll
            for (int n = 0; n < 6; ++n) {
                int c = wc * 96 + n * 16 + g * 4;
                f32x4 a = acc[m][n];
                if (c < 64) {
                    const float4 bb = *(const float4*)(bq + h * 64 + c);
                    *(u32x2*)(qhb + qk_base + c) = (u32x2){
                        pack2((a[0] + bb.x) * 0.125f, (a[1] + bb.y) * 0.125f),
                        pack2((a[2] + bb.z) * 0.125f, (a[3] + bb.w) * 0.125f)};
                } else if (c < 128) {
                    const float4 bb = *(const float4*)(bk + h * 64 + (c - 64));
                    *(u32x2*)(khb + qk_base + (c - 64)) = (u32x2){
                        pack2(a[0] + bb.x, a[1] + bb.y), pack2(a[2] + bb.z, a[3] + bb.w)};
                } else {
                    const float4 bb = *(const float4*)(bv + h * 64 + (c - 128));
                    vtb[v_base + (size_t)(c - 128 + 0) * SKV + s] = f2bf(a[0] + bb.x);
                    vtb[v_base + (size_t)(c - 128 + 1) * SKV + s] = f2bf(a[1] + bb.y);
                    vtb[v_base + (size_t)(c - 128 + 2) * SKV + s] = f2bf(a[2] + bb.z);
                    vtb[v_base + (size_t)(c - 128 + 3) * SKV + s] = f2bf(a[3] + bb.w);
                }
            }
        }
    }
}

// ---------------- MFMA flash attention body: NST q-states per wave share K/V loads ---------
template <int NST>
__device__ __forceinline__ void attn_body(ushort_t* Pl,
                                          const ushort_t* __restrict__ qhp,
                                          const ushort_t* __restrict__ khp,
                                          const ushort_t* __restrict__ vp,
                                          float* __restrict__ tok,
                                          int n, int h, int base, int t) {
    int w = t >> 6, lane = t & 63;
    int lq = lane & 15, g = lane >> 4;
    const int xorm = (lq & 7) << 4;
    char* pw0 = (char*)(Pl + (size_t)w * 3 * 1024);

    short8 qf[NST][2];
    int qr0[NST];
    float m[NST], lsum[NST];
    f32x4 o[NST][4];
#pragma unroll
    for (int s = 0; s < NST; ++s) {
        int qrow = base + s * 64 + w * 16 + lq;
        qr0[s] = qrow;
        int qcl = qrow > 256 ? 256 : qrow;
#pragma unroll
        for (int kk = 0; kk < 2; ++kk)
            qf[s][kk] = *(const short8*)(qhp + (size_t)qcl * 64 + kk * 32 + g * 8);
        m[s] = -INFINITY; lsum[s] = 0.f;
#pragma unroll
        for (int dt = 0; dt < 4; ++dt) o[s][dt] = (f32x4){0.f, 0.f, 0.f, 0.f};
    }

    for (int kt = 0; kt < 5; ++kt) {
        short8 ah[4][2];
#pragma unroll
        for (int st = 0; st < 4; ++st) {
            int key = kt * 64 + st * 16 + lq;
            int kcl = key > 256 ? 256 : key;
            const ushort_t* krh = khp + (size_t)kcl * 64 + g * 8;
            ah[st][0] = *(const short8*)krh;
            ah[st][1] = *(const short8*)(krh + 32);
        }
        f32x4 c[NST][4];
#pragma unroll
        for (int s = 0; s < NST; ++s)
#pragma unroll
            for (int st = 0; st < 4; ++st) {
                c[s][st] = (f32x4){0.f, 0.f, 0.f, 0.f};
#pragma unroll
                for (int kk = 0; kk < 2; ++kk)
                    c[s][st] = __builtin_amdgcn_mfma_f32_16x16x32_bf16(ah[st][kk], qf[s][kk], c[s][st], 0, 0, 0);
            }
        float scale[NST];
        unsigned pw[NST][4][2];
#pragma unroll
        for (int s = 0; s < NST; ++s) {
            float tmax = -INFINITY;
#pragma unroll
            for (int st = 0; st < 4; ++st)
#pragma unroll
                for (int j = 0; j < 4; ++j) {
                    int key = kt * 64 + st * 16 + g * 4 + j;
                    float sv = (key <= 256) ? c[s][st][j] : -INFINITY;
                    c[s][st][j] = sv;
                    tmax = fmaxf(tmax, sv);
                }
            tmax = fmaxf(tmax, __shfl_xor(tmax, 16));
            tmax = fmaxf(tmax, __shfl_xor(tmax, 32));
            float mn = fmaxf(m[s], tmax);
            scale[s] = __expf(m[s] - mn);
            float psum = 0.f;
#pragma unroll
            for (int st = 0; st < 4; ++st) {
                float p0 = __expf(c[s][st][0] - mn), p1 = __expf(c[s][st][1] - mn);
                float p2 = __expf(c[s][st][2] - mn), p3 = __expf(c[s][st][3] - mn);
                psum += (p0 + p1) + (p2 + p3);
                pw[s][st][0] = pack2(p0, p1);
                pw[s][st][1] = pack2(p2, p3);
            }
            psum += __shfl_xor(psum, 16);
            psum += __shfl_xor(psum, 32);
            lsum[s] = lsum[s] * scale[s] + psum;
            m[s] = mn;
        }
#pragma unroll
        for (int s = 0; s < NST; ++s) {
            char* pwave = pw0 + s * 2048;
#pragma unroll
            for (int st = 0; st < 4; ++st) {
                int off = (lq * 128 + st * 32 + g * 8) ^ xorm;
                *(u32x2*)(pwave + off) = (u32x2){pw[s][st][0], pw[s][st][1]};
            }
#pragma unroll
            for (int dt = 0; dt < 4; ++dt) {
                o[s][dt][0] *= scale[s]; o[s][dt][1] *= scale[s];
                o[s][dt][2] *= scale[s]; o[s][dt][3] *= scale[s];
            }
        }
#pragma unroll
        for (int kk = 0; kk < 2; ++kk) {
            short8 pf[NST];
#pragma unroll
            for (int s = 0; s < NST; ++s) {
                int roff = (lq * 128 + kk * 64 + g * 16) ^ xorm;
                pf[s] = *(const short8*)(pw0 + s * 2048 + roff);
            }
#pragma unroll
            for (int dt = 0; dt < 4; ++dt) {
                short8 vf = *(const short8*)(vp + (size_t)(dt * 16 + lq) * SKV + kt * 64 + kk * 32 + g * 8);
#pragma unroll
                for (int s = 0; s < NST; ++s)
                    o[s][dt] = __builtin_amdgcn_mfma_f32_16x16x32_bf16(vf, pf[s], o[s][dt], 0, 0, 0);
            }
        }
    }
#pragma unroll
    for (int s = 0; s < NST; ++s) {
        if (qr0[s] < S_LEN) {
            float inv = 1.0f / lsum[s];
            float* trow = tok + ((size_t)n * S_LEN + qr0[s]) * 768 + h * 64 + g * 4;
#pragma unroll
            for (int dt = 0; dt < 4; ++dt) {
                float4 old = *(const float4*)(trow + dt * 16);
                old.x += o[s][dt][0] * inv;
                old.y += o[s][dt][1] * inv;
                old.z += o[s][dt][2] * inv;
                old.w += o[s][dt][3] * inv;
                *(float4*)(trow + dt * 16) = old;
            }
        }
    }
}

// merged: one 512-thread block per (n,h); waves 0-3 rows [0,128), waves 4-7 rows [128,257]
__global__ __launch_bounds__(512) void attn_fused(const ushort_t* __restrict__ qh,
                                                  const ushort_t* __restrict__ kh,
                                                  const ushort_t* __restrict__ vT,
                                                  float* __restrict__ tok) {
    __shared__ ushort_t Plds[8 * 3 * 1024];
    int nh = blockIdx.x;
    int h = nh % H_HEADS, n = nh / H_HEADS;
    const size_t hoff = ((size_t)n * H_HEADS + h) * (S_LEN * 64);
    const ushort_t* qhp = qh + hoff;
    const ushort_t* khp = kh + hoff;
    const ushort_t* vp  = vT + ((size_t)n * H_HEADS + h) * (64 * SKV);
    int t = threadIdx.x;
    if (t < 256) attn_body<2>(Plds, qhp, khp, vp, tok, n, h, 0, t);
    else         attn_body<3>(Plds + 4 * 3 * 1024, qhp, khp, vp, tok, n, h, 128, t - 256);
}

// ---------------- fast exact-erf GELU (A&S 7.1.26, abs err 1.5e-7) ----------------
__device__ __forceinline__ float gelu_fast(float x) {
    float s = fabsf(x) * 0.70710678118654752f;
    float t = 1.0f / (1.0f + 0.3275911f * s);
    float y = t * (0.254829592f + t * (-0.284496736f + t * (1.421413741f +
              t * (-1.453152027f + t * 1.061405429f))));
    float erfa = 1.0f - y * __expf(-s * s);
    float erfv = copysignf(erfa, x);
    return 0.5f * x * (1.0f + erfv);
}

// ---------------- bf16 MFMA GEMM: 128x128, BK=64, 2-phase, 8 waves (4 waves/SIMD) ----------
// Identical tile/schedule/LDS to the proven round-12 kernel, but 512 threads: each wave
// owns a 32x64 sub-tile (acc[2][4], 16 MFMA + 12 ds_read per iter). 64KB LDS -> 2 blocks/CU
// -> 16 waves/CU = 4 waves/SIMD (vs 2 before): doubled latency-hiding on the same per-iter
// critical path. Same ascending-K accumulation per output element -> bitwise-identical.
// MODE 0: bias+gelu->bf16; MODE 1: +bias, accumulate fp32 into residual.
template <int MODE, int NT>
__global__ __launch_bounds__(512) void mfma_gemm(const ushort_t* __restrict__ A,
                                                 const ushort_t* __restrict__ B,
                                                 const float* __restrict__ bias,
                                                 void* __restrict__ Cv,
                                                 int lda, int ldb, int ldc, int nbn) {
    __shared__ ushort_t SMEM[4][8192];   // [0..1]: A slots, [2..3]: B slots (64 KB)
    int nwg = gridDim.x;
    int orig = blockIdx.x;
    int xcd = orig & 7, idx = orig >> 3;
    int q8 = nwg >> 3, r8 = nwg & 7;
    int cbase = (xcd < r8) ? xcd * (q8 + 1) : r8 * (q8 + 1) + (xcd - r8) * q8;
    int swb = cbase + idx;
    int bm = swb / nbn, bn = swb - bm * nbn;

    int t = threadIdx.x;
    int lane = t & 63, wid = t >> 6;         // 8 waves
    int wr = wid >> 1, wc = wid & 1;         // wave tile: 32 rows x 64 cols
    int srow = t >> 3;                       // 0..63 (512 threads)
    int swzo = ((t & 7) ^ (srow & 7)) * 8;   // source pre-swizzle (matches read XOR)
    int wbase = (t & 448) * 8;               // wave-uniform LDS chunk base = w*512 shorts
    int frow = lane & 15, g = lane >> 4;

    const ushort_t* pA[2];
    const ushort_t* pB[2];
#pragma unroll
    for (int u = 0; u < 2; ++u) {
        pA[u] = A + (size_t)(bm * 128 + u * 64 + srow) * lda + swzo;
        pB[u] = B + (size_t)(bn * 128 + u * 64 + srow) * ldb + swzo;
    }
    int offA[2][2], offB[4][2];
#pragma unroll
    for (int kk = 0; kk < 2; ++kk) {
#pragma unroll
        for (int m = 0; m < 2; ++m) {
            int ra = wr * 32 + m * 16 + frow;
            offA[m][kk] = ra * 64 + ((kk * 4 + g) ^ (ra & 7)) * 8;
        }
#pragma unroll
        for (int n = 0; n < 4; ++n) {
            int rb = wc * 64 + n * 16 + frow;
            offB[n][kk] = rb * 64 + ((kk * 4 + g) ^ (rb & 7)) * 8;
        }
    }

    f32x4 acc[2][4];
#pragma unroll
    for (int m = 0; m < 2; ++m)
#pragma unroll
        for (int n = 0; n < 4; ++n) acc[m][n] = (f32x4){0.f, 0.f, 0.f, 0.f};

    auto STAGE = [&](int buf, int koff) {
#pragma unroll
        for (int u = 0; u < 2; ++u) {
            glds16(pA[u] + koff, &SMEM[buf][u * 4096 + wbase]);
            glds16(pB[u] + koff, &SMEM[2 + buf][u * 4096 + wbase]);
        }
    };
    auto COMPUTE = [&](int cur) {
#pragma unroll
        for (int kk = 0; kk < 2; ++kk) {
            short8 af[2], bf[4];
#pragma unroll
            for (int mi = 0; mi < 2; ++mi) af[mi] = *(const short8*)&SMEM[cur][offA[mi][kk]];
#pragma unroll
            for (int ni = 0; ni < 4; ++ni) bf[ni] = *(const short8*)&SMEM[2 + cur][offB[ni][kk]];
            // swapped: C[row=A-row(frow)][col=B-row(g*4+j)]
#pragma unroll
            for (int mi = 0; mi < 2; ++mi)
#pragma unroll
                for (int ni = 0; ni < 4; ++ni)
                    acc[mi][ni] = __builtin_amdgcn_mfma_f32_16x16x32_bf16(bf[ni], af[mi], acc[mi][ni], 0, 0, 0);
        }
    };

    STAGE(0, 0);
    asm volatile("s_waitcnt vmcnt(0)" ::: "memory");
    __builtin_amdgcn_s_barrier();

    constexpr int NOUT = NT / 12;
    for (int ot = 0; ot < NOUT - 1; ++ot) {
#pragma unroll
        for (int ii = 0; ii < 12; ++ii) {
            STAGE((ii + 1) & 1, (ii + 1) * 64);
            COMPUTE(ii & 1);
            asm volatile("s_waitcnt vmcnt(0) lgkmcnt(0)" ::: "memory");
            __builtin_amdgcn_s_barrier();
        }
#pragma unroll
        for (int u = 0; u < 2; ++u) { pA[u] += 12 * 64; pB[u] += 12 * 64; }
    }
#pragma unroll
    for (int ii = 0; ii < 12; ++ii) {
        if (ii + 1 < 12) STAGE((ii + 1) & 1, (ii + 1) * 64);
        COMPUTE(ii & 1);
        if (ii + 1 < 12) {
            asm volatile("s_waitcnt vmcnt(0) lgkmcnt(0)" ::: "memory");
            __builtin_amdgcn_s_barrier();
        }
    }

    int row0 = bm * 128 + wr * 32 + frow;
    int col0 = bn * 128 + wc * 64 + g * 4;
#pragma unroll
    for (int n = 0; n < 4; ++n) {
        int col = col0 + n * 16;
        float4 bb = {0.f, 0.f, 0.f, 0.f};
        if (bias) bb = *(const float4*)(bias + col);
#pragma unroll
        for (int mi = 0; mi < 2; ++mi) {
            int row = row0 + mi * 16;
            f32x4 a = acc[mi][n];
            float v0 = a[0] + bb.x, v1 = a[1] + bb.y, v2 = a[2] + bb.z, v3 = a[3] + bb.w;
            if (MODE == 0) {
                v0 = gelu_fast(v0); v1 = gelu_fast(v1); v2 = gelu_fast(v2); v3 = gelu_fast(v3);
                *(u32x2*)((ushort_t*)Cv + (size_t)row * ldc + col) =
                    (u32x2){pack2(v0, v1), pack2(v2, v3)};
            } else {
                float* cp = (float*)Cv + (size_t)row * ldc + col;
                float4 old = *(const float4*)cp;
                old.x += v0; old.y += v1; old.z += v2; old.w += v3;
                *(float4*)cp = old;
            }
        }
    }
}

// ---------------- classifier head + softmax ----------------
__global__ __launch_bounds__(64) void head_kernel(const float* __restrict__ tok,
                                                  const float* __restrict__ Whead,
                                                  const float* __restrict__ bhead,
                                                  float* __restrict__ out) {
    int n = blockIdx.x;
    int t = threadIdx.x;
    __shared__ float logits[OUT_DIM];
    if (t < OUT_DIM) {
        float acc = bhead[t];
        const float* xr = tok + (size_t)n * S_LEN * 768;
        const float* w = Whead + t * 768;
        for (int d = 0; d < 768; ++d) acc += xr[d] * w[d];
        logits[t] = acc;
    }
    __syncthreads();
    if (t == 0) {
        float m = -INFINITY;
        for (int o = 0; o < OUT_DIM; ++o) m = fmaxf(m, logits[o]);
        float ssum = 0.f;
        float e[OUT_DIM];
        for (int o = 0; o < OUT_DIM; ++o) { e[o] = expf(logits[o] - m); ssum += e[o]; }
        float inv = 1.0f / ssum;
        for (int o = 0; o < OUT_DIM; ++o) out[n * OUT_DIM + o] = e[o] * inv;
    }
}

extern "C" void kernel_launch(void* const* d_in, const int* in_sizes, int n_in,
                              void* d_out, int out_size, void* d_ws, size_t ws_size,
                              hipStream_t stream) {
    const float* images = (const float*)d_in[0];
    const float* Wemb   = (const float*)d_in[1];
    const float* bemb   = (const float*)d_in[2];
    const float* cls    = (const float*)d_in[3];
    const float* Wq     = (const float*)d_in[4];
    const float* bq     = (const float*)d_in[5];
    const float* Wk     = (const float*)d_in[6];
    const float* bk     = (const float*)d_in[7];
    const float* Wv     = (const float*)d_in[8];
    const float* bv     = (const float*)d_in[9];
    const float* ln1_g  = (const float*)d_in[10];
    const float* ln1_b  = (const float*)d_in[11];
    const float* ln2_g  = (const float*)d_in[12];
    const float* ln2_b  = (const float*)d_in[13];
    const float* W1     = (const float*)d_in[14];
    const float* b1     = (const float*)d_in[15];
    const float* W2     = (const float*)d_in[16];
    const float* b2     = (const float*)d_in[17];
    const float* Whead  = (const float*)d_in[18];
    const float* bhead  = (const float*)d_in[19];
    float* out = (float*)d_out;

    const size_t TOKP = (size_t)R_PAD * D_MODEL;               // 12,681,216
    const size_t QKSZ = (size_t)N_IMG * H_HEADS * S_LEN * 64;  // 12,632,064
    const size_t VTSZ = (size_t)N_IMG * H_HEADS * 64 * SKV;    // 15,728,640
    const size_t WSZ  = (size_t)F_HID * D_MODEL;               // 2,359,296
    float* ws   = (float*)d_ws;
    float* pos  = ws;                                          // 197,376 f32
    float* tok  = pos + 197376;                                // TOKP f32
    ushort_t* xbf  = (ushort_t*)(tok + TOKP);                  // TOKP bf16
    ushort_t* qhb  = xbf + TOKP;                               // QKSZ
    ushort_t* khb  = qhb + QKSZ;                               // QKSZ
    ushort_t* vtb  = khb + QKSZ;                               // VTSZ
    ushort_t* wqkvbf = vtb + VTSZ;                             // 147,456
    ushort_t* w1bf = wqkvbf + H_HEADS * 192 * 64;              // full layer W1
    ushort_t* w2bf = w1bf + WSZ;                               // full layer W2
    ushort_t* hid_full = w2bf + WSZ;                           // R_PAD*F_HID bf16 (if ws allows)

    const size_t hid_bytes = (size_t)R_PAD * F_HID * 2;
    const size_t needed = ((char*)hid_full - (char*)d_ws) + hid_bytes;
    int nchunk = (ws_size >= needed) ? 1 : 2;
    ushort_t* hid = (nchunk == 1) ? hid_full : qhb;   // fallback: overlay q/k region

    pos_kernel<<<S_LEN, 256, 0, stream>>>(pos);
    embed_kernel<<<R_ROWS, 256, 0, stream>>>(images, Wemb, bemb, cls, pos, tok);

    for (int l = 0; l < L_LAYERS; ++l) {
        const size_t wqkv_off = (size_t)l * H_HEADS * 64 * 64;
        const size_t bqkv_off = (size_t)l * H_HEADS * 64;
        ln_kernel<<<R_ROWS / 4, 256, 0, stream>>>(tok, ln1_g + l * 768, ln1_b + l * 768, xbf);
        conv_layer<<<4752, 256, 0, stream>>>(
            Wq + wqkv_off, Wk + wqkv_off, Wv + wqkv_off,
            W1 + (size_t)l * WSZ, W2 + (size_t)l * WSZ,
            wqkvbf, w1bf, w2bf);
        qkv_mfma<<<dim3(R_PAD / 128, H_HEADS), 256, 0, stream>>>(
            xbf, wqkvbf, bq + bqkv_off, bk + bqkv_off, bv + bqkv_off, qhb, khb, vtb);
        attn_fused<<<N_IMG * H_HEADS, 512, 0, stream>>>(qhb, khb, vtb, tok);
        ln_kernel<<<R_ROWS / 4, 256, 0, stream>>>(tok, ln2_g + l * 768, ln2_b + l * 768, xbf);
        if (nchunk == 1) {
            mfma_gemm<0, 12><<<(F_HID / 128) * (R_PAD / 128), 512, 0, stream>>>(
                xbf, w1bf, b1 + (size_t)l * F_HID, hid, 768, 768, F_HID, F_HID / 128);
            mfma_gemm<1, 48><<<(D_MODEL / 128) * (R_PAD / 128), 512, 0, stream>>>(
                hid, w2bf, b2 + (size_t)l * D_MODEL, tok, F_HID, F_HID, D_MODEL,
                D_MODEL / 128);
        } else {
            const int FC = F_HID / 2;
            for (int c = 0; c < 2; ++c) {
                int c0 = c * FC;
                mfma_gemm<0, 12><<<(FC / 128) * (R_PAD / 128), 512, 0, stream>>>(
                    xbf, w1bf + (size_t)c0 * D_MODEL, b1 + (size_t)l * F_HID + c0, hid,
                    768, 768, FC, FC / 128);
                mfma_gemm<1, 24><<<(D_MODEL / 128) * (R_PAD / 128), 512, 0, stream>>>(
                    hid, w2bf + c0,
                    (c == 0) ? (b2 + (size_t)l * D_MODEL) : (const float*)nullptr,
                    tok, FC, F_HID, D_MODEL, D_MODEL / 128);
            }
        }
    }
    head_kernel<<<N_IMG, 64, 0, stream>>>(tok, Whead, bhead, out);
}